// Round 15
// baseline (248.812 us; speedup 1.0000x reference)
//
#include <hip/hip_runtime.h>
#include <hip/hip_bf16.h>
#include <math.h>

#define NN   10000
#define EE   160000
#define ETOT 170000
#define FIN  128
#define C1   1024   // H1*D1
#define NH1  4
#define D1   256
#define D2   256

typedef __attribute__((ext_vector_type(8))) short bf16x8;
typedef __attribute__((ext_vector_type(4))) float f32x4;

// ---------------- bf16 helpers ----------------
__device__ __forceinline__ float b2f(unsigned short u)
{
    union { unsigned int i; float f; } c; c.i = (unsigned int)u << 16; return c.f;
}
__device__ __forceinline__ unsigned short f2b(float x)
{
    return __builtin_bit_cast(unsigned short, __float2bfloat16(x));
}
__device__ __forceinline__ void split1(float x, unsigned short &h, unsigned short &l)
{
    __hip_bfloat16 hb = __float2bfloat16(x);
    float r = x - __bfloat162float(hb);
    h = __builtin_bit_cast(unsigned short, hb);
    l = __builtin_bit_cast(unsigned short, __float2bfloat16(r));
}

// ================= fused prep =================
// ranges: [0,1250) split_A(x) ; [1250,1506) Bt1 stack ; [1506,2018) Bt2 ;
//         [2018,2683) count_deg ; [2683,2939) proj1 ; [2939,3451) proj2
__device__ __forceinline__ void split_A_body(const float* __restrict__ X,
                                             unsigned short* __restrict__ A2,
                                             int M, int K, int idx)
{
    int kq4 = K >> 2;
    if (idx >= M * kq4) return;
    int m = idx / kq4, kq = idx % kq4;
    float4 v = *(const float4*)&X[(size_t)m * K + kq * 4];
    ushort4 h, l;
    split1(v.x, h.x, l.x); split1(v.y, h.y, l.y);
    split1(v.z, h.z, l.z); split1(v.w, h.w, l.w);
    unsigned short* row = A2 + (size_t)m * (2 * K);
    *(ushort4*)&row[kq * 4]     = h;
    *(ushort4*)&row[K + kq * 4] = l;
}

__device__ __forceinline__ void split_Bt_body(const float* __restrict__ B0,
                                              const float* __restrict__ B1,
                                              int K, int N0, int Ntot,
                                              unsigned short* __restrict__ Bt, int idx)
{
    int total = Ntot * (K >> 2);
    if (idx >= total) return;
    int n = idx % Ntot;
    int kq = idx / Ntot;
    int k = kq * 4;
    const float* B; int nc, nb;
    if (n < N0) { B = B0; nc = n; nb = N0; }
    else        { B = B1; nc = n - N0; nb = Ntot - N0; }
    float v0 = B[(size_t)(k + 0) * nb + nc];
    float v1 = B[(size_t)(k + 1) * nb + nc];
    float v2 = B[(size_t)(k + 2) * nb + nc];
    float v3 = B[(size_t)(k + 3) * nb + nc];
    ushort4 h, l;
    split1(v0, h.x, l.x); split1(v1, h.y, l.y);
    split1(v2, h.z, l.z); split1(v3, h.w, l.w);
    unsigned short* row = Bt + (size_t)n * (3 * K);
    *(ushort4*)&row[k]         = h;
    *(ushort4*)&row[K + k]     = h;
    *(ushort4*)&row[2 * K + k] = l;
}

// Bt1: stacked [W1; lin1W] (K=256, N=1024) -> rows [bhi(256)|bhi(256)|blo(256)]
__device__ __forceinline__ void split_Bt1_body(const float* __restrict__ W1,
                                               const float* __restrict__ lin1W,
                                               unsigned short* __restrict__ Bt, int idx)
{
    if (idx >= 1024 * 64) return;
    int n = idx & 1023;
    int k = (idx >> 10) * 4;     // 0..252
    float v[4];
    #pragma unroll
    for (int i = 0; i < 4; ++i) {
        int kk = k + i;
        v[i] = (kk < 128) ? W1[(size_t)kk * C1 + n] : lin1W[(size_t)(kk - 128) * C1 + n];
    }
    ushort4 h, l;
    split1(v[0], h.x, l.x); split1(v[1], h.y, l.y);
    split1(v[2], h.z, l.z); split1(v[3], h.w, l.w);
    unsigned short* row = Bt + (size_t)n * 768;
    *(ushort4*)&row[k]       = h;
    *(ushort4*)&row[256 + k] = h;
    *(ushort4*)&row[512 + k] = l;
}

__global__ __launch_bounds__(256)
void prep(const float* __restrict__ x, unsigned short* __restrict__ A1stk,
          const float* __restrict__ W1, const float* __restrict__ lin1_W,
          unsigned short* __restrict__ Bt1,
          const float* __restrict__ W2, const float* __restrict__ lin2_W,
          unsigned short* __restrict__ Bt2,
          const int* __restrict__ dstp, int* __restrict__ cnt,
          const float* __restrict__ as1, const float* __restrict__ ad1,
          float* __restrict__ w1s, float* __restrict__ w1d,
          const float* __restrict__ as2, const float* __restrict__ ad2,
          float* __restrict__ v2s, float* __restrict__ v2d)
{
    const int b = blockIdx.x, t = threadIdx.x;
    const int w = t >> 6, lane = t & 63;
    if (b < 1250) {
        split_A_body(x, A1stk, NN, FIN, b * 256 + t);
    } else if (b < 1506) {
        split_Bt1_body(W1, lin1_W, Bt1, (b - 1250) * 256 + t);
    } else if (b < 2018) {
        split_Bt_body(W2, lin2_W, C1, D2, 512, Bt2, (b - 1506) * 256 + t);
    } else if (b < 2683) {
        int e = (b - 2018) * 256 + t;
        if (e < ETOT) {
            int d = (e < EE) ? dstp[e] : (e - EE);
            atomicAdd(&cnt[d], 1);
        }
    } else if (b < 2939) {
        int gw = (b - 2683) * 4 + w;
        int k = gw >> 3, rem = gw & 7, h = rem >> 1, issd = rem & 1;
        const float* a = issd ? ad1 : as1;
        float4 wv = *(const float4*)&W1[(size_t)k * C1 + h * 256 + lane * 4];
        float4 av = *(const float4*)&a[h * 256 + lane * 4];
        float s = wv.x * av.x + wv.y * av.y + wv.z * av.z + wv.w * av.w;
        #pragma unroll
        for (int off = 32; off; off >>= 1) s += __shfl_xor(s, off);
        if (lane == 0) (issd ? w1d : w1s)[k * 4 + h] = s;
    } else {
        int gw = (b - 2939) * 4 + w;
        int k = gw >> 1, issd = gw & 1;
        const float* a = issd ? ad2 : as2;
        float4 wv = *(const float4*)&W2[(size_t)k * D2 + lane * 4];
        float4 av = *(const float4*)&a[lane * 4];
        float s = wv.x * av.x + wv.y * av.y + wv.z * av.z + wv.w * av.w;
        #pragma unroll
        for (int off = 32; off; off >>= 1) s += __shfl_xor(s, off);
        if (lane == 0) (issd ? v2d : v2s)[k] = s;
    }
}

// ================= GEMMs =================
__device__ __forceinline__ void glds16(const void* g, void* l)
{
    __builtin_amdgcn_global_load_lds((const __attribute__((address_space(1))) void*)g,
                                     (__attribute__((address_space(3))) void*)l, 16, 0, 0);
}

// ---- layer-1 GEMM: per-head A = [px_h | x] split-bf16, keff=768, out = ELU(.)+biases
__global__ __launch_bounds__(256)
void gemm_l1(const unsigned short* __restrict__ Apx,   // [NN][4*256] per-head [hi128|lo128]
             const unsigned short* __restrict__ Ax,    // [NN][256]  [xhi|xlo]
             const unsigned short* __restrict__ Bt,    // [1024][768]
             unsigned short* __restrict__ h1split,     // [NN][2048] [hi1024|lo1024]
             int M, const float* __restrict__ bias0, const float* __restrict__ bias1)
{
    constexpr int BM = 128, BN = 128, BK = 32;
    constexpr int FJ = 4, FI = 4;
    constexpr int SLOTS = 4, SMASK = 3, SWSH = 1;
    constexpr int RPC = 16, ACH = 8, CPW = 4;
    constexpr int ABUF = BM * BK, BBUF = BN * BK;
    __shared__ __align__(16) unsigned short sA[2 * ABUF];
    __shared__ __align__(16) unsigned short sB[2 * BBUF];
    const int tid = threadIdx.x, w = tid >> 6, lane = tid & 63;
    const int cpx = gridDim.x >> 3;
    const int t0 = (blockIdx.x & 7) * cpx + (blockIdx.x >> 3);
    const int m0 = (t0 >> 3) * BM;          // ntn = 8
    const int n0 = (t0 & 7) * BN;
    const int hsel = n0 >> 8;               // head
    const int wm = w >> 1, wn = w & 1;
    f32x4 acc[FI][FJ] = {};

    const unsigned short *gx[CPW], *gpx[CPW], *gb[CPW];
    int lofs[CPW]; bool isa[CPW];
    {
        const int r = lane / SLOTS, sl = lane % SLOTS;
        const int ssl = sl ^ ((r >> SWSH) & SMASK);
        #pragma unroll
        for (int cc = 0; cc < CPW; ++cc) {
            int c = w * CPW + cc;
            if (c < ACH) {
                int gm = m0 + c * RPC + r; if (gm >= M) gm = M - 1;
                gx[cc]  = Ax  + (size_t)gm * 256 + ssl * 8;
                gpx[cc] = Apx + (size_t)gm * 1024 + hsel * 256 + ssl * 8;
                gb[cc]  = nullptr;
                lofs[cc] = c * 512;
                isa[cc] = true;
            } else {
                int gn = n0 + (c - ACH) * RPC + r;
                gx[cc] = gpx[cc] = nullptr;
                gb[cc] = Bt + (size_t)gn * 768 + ssl * 8;
                lofs[cc] = (c - ACH) * 512;
                isa[cc] = false;
            }
        }
    }

    const int rAl = wm * 64 + (lane & 15);
    const int rBl = wn * 64 + (lane & 15);
    const int sIdx = lane >> 4;
    const int nit = 768 / BK;               // 24
    int cur = 0;

    auto stage = [&](int kk, int buf) {
        int rr = kk >> 7;                   // 0..5
        bool px = !(rr & 1);
        int off = px ? ((rr == 2) ? 128 : 0) : ((rr == 3) ? 128 : 0);
        int kin = kk & 127;
        #pragma unroll
        for (int cc = 0; cc < CPW; ++cc) {
            if (isa[cc]) glds16((px ? gpx[cc] : gx[cc]) + off + kin, sA + buf * ABUF + lofs[cc]);
            else         glds16(gb[cc] + kk,                         sB + buf * BBUF + lofs[cc]);
        }
    };

    stage(0, 0);
    __syncthreads();
    for (int it = 0; it < nit; ++it) {
        if (it + 1 < nit) stage((it + 1) * BK, cur ^ 1);
        const unsigned short* cA = sA + cur * ABUF;
        const unsigned short* cB = sB + cur * BBUF;
        bf16x8 av[FJ], bv[FI];
        #pragma unroll
        for (int f = 0; f < FI; ++f) {
            int row = rBl + f * 16;
            bv[f] = *(const bf16x8*)&cB[row * BK + ((sIdx ^ ((row >> SWSH) & SMASK)) << 3)];
        }
        #pragma unroll
        for (int f = 0; f < FJ; ++f) {
            int row = rAl + f * 16;
            av[f] = *(const bf16x8*)&cA[row * BK + ((sIdx ^ ((row >> SWSH) & SMASK)) << 3)];
        }
        #pragma unroll
        for (int fj = 0; fj < FJ; ++fj)
            #pragma unroll
            for (int fi = 0; fi < FI; ++fi)
                acc[fi][fj] = __builtin_amdgcn_mfma_f32_16x16x32_bf16(
                    bv[fi], av[fj], acc[fi][fj], 0, 0, 0);
        __syncthreads();
        cur ^= 1;
    }

    const int lrow = lane & 15;
    const int lcol = (lane >> 4) << 2;
    #pragma unroll
    for (int fj = 0; fj < FJ; ++fj) {
        int row = m0 + wm * 64 + fj * 16 + lrow;
        if (row >= M) continue;
        #pragma unroll
        for (int fi = 0; fi < FI; ++fi) {
            int col = n0 + wn * 64 + fi * 16 + lcol;
            f32x4 v = acc[fi][fj];
            const float4 g0 = *(const float4*)&bias0[col];
            const float4 g1 = *(const float4*)&bias1[col];
            v[0] += g0.x + g1.x; v[1] += g0.y + g1.y;
            v[2] += g0.z + g1.z; v[3] += g0.w + g1.w;
            #pragma unroll
            for (int i = 0; i < 4; ++i) v[i] = v[i] > 0.f ? v[i] : expm1f(v[i]);
            ushort4 hi, lo;
            split1(v[0], hi.x, lo.x); split1(v[1], hi.y, lo.y);
            split1(v[2], hi.z, lo.z); split1(v[3], hi.w, lo.w);
            unsigned short* orow = h1split + (size_t)row * 2048;
            *(ushort4*)&orow[col]        = hi;
            *(ushort4*)&orow[C1 + col]   = lo;
        }
    }
}

// ---- generic split-bf16 GEMM (layer 2), BM templated for grid-size control ----
template<int BM, int BN, int WM, int WN, int BK>
__global__ __launch_bounds__(256)
void gemm_split(const unsigned short* __restrict__ A, int lda, int ka2,
                const unsigned short* __restrict__ Bt, int keff,
                unsigned short* __restrict__ outPb, float* __restrict__ outR,
                int M, int nsplit, int ldR, int ntn,
                const float* __restrict__ bias0, const float* __restrict__ bias1)
{
    constexpr int WTM  = BM / WM,  WTN = BN / WN;
    constexpr int FJ   = WTM / 16, FI  = WTN / 16;
    constexpr int KS   = BK / 32;
    constexpr int SLOTS = BK / 8;
    constexpr int SMASK = SLOTS - 1;
    constexpr int SWSH  = (BK == 32) ? 1 : 0;
    constexpr int RPC  = 512 / BK;
    constexpr int ACH  = BM / RPC;
    constexpr int NCH  = (BM + BN) / RPC;
    constexpr int CPW  = NCH / 4;
    constexpr int ABUF = BM * BK, BBUF = BN * BK;

    __shared__ __align__(16) unsigned short sA[2 * ABUF];
    __shared__ __align__(16) unsigned short sB[2 * BBUF];

    const int tid = threadIdx.x;
    const int w = tid >> 6, lane = tid & 63;

    const int cpx = gridDim.x >> 3;
    const int t0  = (blockIdx.x & 7) * cpx + (blockIdx.x >> 3);
    const int m0 = (t0 / ntn) * BM;
    const int n0 = (t0 % ntn) * BN;
    const int wm = w / WN, wn = w % WN;

    f32x4 acc[FI][FJ] = {};

    const unsigned short* gp[CPW];
    int lofs[CPW];
    bool isa[CPW];
    {
        const int r  = lane / SLOTS;
        const int sl = lane % SLOTS;
        const int ssl = sl ^ ((r >> SWSH) & SMASK);
        #pragma unroll
        for (int cc = 0; cc < CPW; ++cc) {
            int c = w * CPW + cc;
            if (c < ACH) {
                int gm = m0 + c * RPC + r; if (gm >= M) gm = M - 1;
                gp[cc]   = A + (size_t)gm * lda + ssl * 8;
                lofs[cc] = c * 512;
                isa[cc]  = true;
            } else {
                int gn = n0 + (c - ACH) * RPC + r;
                gp[cc]   = Bt + (size_t)gn * keff + ssl * 8;
                lofs[cc] = (c - ACH) * 512;
                isa[cc]  = false;
            }
        }
    }

    const int rAl = wm * WTM + (lane & 15);
    const int rBl = wn * WTN + (lane & 15);
    const int koff = (lane >> 4) * 8;
    const int nit = keff / BK;
    int cur = 0;

    #pragma unroll
    for (int cc = 0; cc < CPW; ++cc)
        glds16(gp[cc], (isa[cc] ? sA : sB) + lofs[cc]);
    __syncthreads();

    for (int it = 0; it < nit; ++it) {
        if (it + 1 < nit) {
            int kn = (it + 1) * BK;
            int kAn = (kn >= ka2) ? (kn - ka2) : kn;
            #pragma unroll
            for (int cc = 0; cc < CPW; ++cc) {
                unsigned short* dst = (isa[cc] ? sA + (cur ^ 1) * ABUF
                                               : sB + (cur ^ 1) * BBUF) + lofs[cc];
                glds16(gp[cc] + (isa[cc] ? kAn : kn), dst);
            }
        }
        const unsigned short* cA = sA + cur * ABUF;
        const unsigned short* cB = sB + cur * BBUF;
        #pragma unroll
        for (int ks = 0; ks < KS; ++ks) {
            const int sIdx = (ks * 32 + koff) >> 3;
            bf16x8 av[FJ], bv[FI];
            #pragma unroll
            for (int f = 0; f < FI; ++f) {
                int row = rBl + f * 16;
                bv[f] = *(const bf16x8*)&cB[row * BK + ((sIdx ^ ((row >> SWSH) & SMASK)) << 3)];
            }
            #pragma unroll
            for (int f = 0; f < FJ; ++f) {
                int row = rAl + f * 16;
                av[f] = *(const bf16x8*)&cA[row * BK + ((sIdx ^ ((row >> SWSH) & SMASK)) << 3)];
            }
            #pragma unroll
            for (int fj = 0; fj < FJ; ++fj)
                #pragma unroll
                for (int fi = 0; fi < FI; ++fi)
                    acc[fi][fj] = __builtin_amdgcn_mfma_f32_16x16x32_bf16(
                        bv[fi], av[fj], acc[fi][fj], 0, 0, 0);
        }
        __syncthreads();
        cur ^= 1;
    }

    const int lrow = lane & 15;
    const int lcol = (lane >> 4) << 2;
    #pragma unroll
    for (int fj = 0; fj < FJ; ++fj) {
        int row = m0 + wm * WTM + fj * 16 + lrow;
        if (row >= M) continue;
        #pragma unroll
        for (int fi = 0; fi < FI; ++fi) {
            int col = n0 + wn * WTN + fi * 16 + lcol;
            f32x4 v = acc[fi][fj];
            if (col < nsplit) {
                ushort4 o;
                o.x = f2b(v[0]); o.y = f2b(v[1]); o.z = f2b(v[2]); o.w = f2b(v[3]);
                *(ushort4*)&outPb[(size_t)row * nsplit + col] = o;
            } else {
                int c = col - nsplit;
                const float4 g0 = *(const float4*)&bias0[c];
                const float4 g1 = *(const float4*)&bias1[c];
                v[0] += g0.x + g1.x; v[1] += g0.y + g1.y;
                v[2] += g0.z + g1.z; v[3] += g0.w + g1.w;
                *(f32x4*)&outR[(size_t)row * ldR + c] = v;
            }
        }
    }
}

// ================= scores =================
__global__ __launch_bounds__(256)
void s1_scores(const float* __restrict__ x, const float* __restrict__ w1s,
               const float* __restrict__ w1d, float* __restrict__ s_src,
               float* __restrict__ s_dst)
{
    const int n = blockIdx.x * 4 + (threadIdx.x >> 6);
    if (n >= NN) return;
    const int lane = threadIdx.x & 63;
    float2 xv = *(const float2*)&x[(size_t)n * FIN + lane * 2];
    float4 wa = *(const float4*)&w1s[(lane * 2) * 4];
    float4 wb = *(const float4*)&w1s[(lane * 2 + 1) * 4];
    float4 da = *(const float4*)&w1d[(lane * 2) * 4];
    float4 db = *(const float4*)&w1d[(lane * 2 + 1) * 4];
    float ss[4] = { xv.x * wa.x + xv.y * wb.x, xv.x * wa.y + xv.y * wb.y,
                    xv.x * wa.z + xv.y * wb.z, xv.x * wa.w + xv.y * wb.w };
    float sd[4] = { xv.x * da.x + xv.y * db.x, xv.x * da.y + xv.y * db.y,
                    xv.x * da.z + xv.y * db.z, xv.x * da.w + xv.y * db.w };
    #pragma unroll
    for (int off = 32; off; off >>= 1) {
        #pragma unroll
        for (int h = 0; h < 4; ++h) {
            ss[h] += __shfl_xor(ss[h], off);
            sd[h] += __shfl_xor(sd[h], off);
        }
    }
    if (lane == 0) {
        #pragma unroll
        for (int h = 0; h < 4; ++h) {
            s_src[n * NH1 + h] = ss[h];
            s_dst[n * NH1 + h] = sd[h];
        }
    }
}

__global__ __launch_bounds__(256)
void scores2(const unsigned short* __restrict__ h1split, const float* __restrict__ v2s,
             const float* __restrict__ v2d, float* __restrict__ s_src,
             float* __restrict__ s_dst)
{
    const int n = blockIdx.x * 4 + (threadIdx.x >> 6);
    if (n >= NN) return;
    const int lane = threadIdx.x & 63;
    const unsigned short* row = h1split + (size_t)n * 2048 + lane * 16;
    float ss = 0.f, sd = 0.f;
    #pragma unroll
    for (int q = 0; q < 16; ++q) {
        float hv = b2f(row[q]);
        ss += hv * v2s[lane * 16 + q];
        sd += hv * v2d[lane * 16 + q];
    }
    #pragma unroll
    for (int off = 32; off; off >>= 1) {
        ss += __shfl_xor(ss, off);
        sd += __shfl_xor(sd, off);
    }
    if (lane == 0) { s_src[n] = ss; s_dst[n] = sd; }
}

// ================= CSR =================
__global__ __launch_bounds__(1024)
void scan_kernel(const int* __restrict__ cnt, int* __restrict__ row_ptr)
{
    __shared__ int part[1024];
    const int t = threadIdx.x;
    int local[10];
    int s = 0;
    #pragma unroll
    for (int j = 0; j < 10; ++j) {
        int idx = t * 10 + j;
        local[j] = s;
        s += (idx < NN) ? cnt[idx] : 0;
    }
    part[t] = s;
    __syncthreads();
    for (int off = 1; off < 1024; off <<= 1) {
        int v = (t >= off) ? part[t - off] : 0;
        __syncthreads();
        part[t] += v;
        __syncthreads();
    }
    int prefix = (t > 0) ? part[t - 1] : 0;
    #pragma unroll
    for (int j = 0; j < 10; ++j) {
        int idx = t * 10 + j;
        if (idx < NN) row_ptr[idx] = prefix + local[j];
    }
    if (t == 0) row_ptr[NN] = ETOT;
}

// scatter + edge-parallel layer-1 score precompute (post-lrelu), contiguous in CSR order
__global__ void scatter_edges(const int* __restrict__ srcp, const int* __restrict__ dstp,
                              const int* __restrict__ row_ptr, int* __restrict__ fill,
                              int* __restrict__ csr_src, int* __restrict__ csr_eid,
                              int* __restrict__ csr_dst,
                              const float* __restrict__ s_src1,
                              const float* __restrict__ s_dst1,
                              float* __restrict__ sc1)
{
    int e = blockIdx.x * 256 + threadIdx.x;
    if (e >= ETOT) return;
    int s, d;
    if (e < EE) { s = srcp[e]; d = dstp[e]; } else { s = d = e - EE; }
    int pos = row_ptr[d] + atomicAdd(&fill[d], 1);
    csr_src[pos] = s;
    csr_eid[pos] = e;
    csr_dst[pos] = d;
    float4 ss = *(const float4*)&s_src1[s * 4];
    float4 dd = *(const float4*)&s_dst1[d * 4];
    float4 sc;
    sc.x = ss.x + dd.x; sc.y = ss.y + dd.y;
    sc.z = ss.z + dd.z; sc.w = ss.w + dd.w;
    sc.x = sc.x > 0.f ? sc.x : 0.2f * sc.x;
    sc.y = sc.y > 0.f ? sc.y : 0.2f * sc.y;
    sc.z = sc.z > 0.f ? sc.z : 0.2f * sc.z;
    sc.w = sc.w > 0.f ? sc.w : 0.2f * sc.w;
    *(float4*)&sc1[(size_t)pos * 4] = sc;
}

// edge-parallel layer-2 score precompute
__global__ void sc2_kernel(const int* __restrict__ csr_src, const int* __restrict__ csr_dst,
                           const float* __restrict__ s_src2, const float* __restrict__ s_dst2,
                           float* __restrict__ sc2)
{
    int j = blockIdx.x * 256 + threadIdx.x;
    if (j >= ETOT) return;
    float sc = s_src2[csr_src[j]] + s_dst2[csr_dst[j]];
    sc2[j] = sc > 0.f ? sc : 0.2f * sc;
}

// ===== node-parallel m,1/z for layer 1 + fused alpha1 write =====
__global__ __launch_bounds__(256)
void mz1_alpha(const float* __restrict__ sc1, const int* __restrict__ row_ptr,
               const int* __restrict__ csr_eid, float* __restrict__ mz1,
               float* __restrict__ alpha_out)
{
    const int n = blockIdx.x * 4 + (threadIdx.x >> 6);
    if (n >= NN) return;
    const int lane = threadIdx.x & 63;
    const int start = row_ptr[n], end = row_ptr[n + 1];
    float4 m = make_float4(-1e30f, -1e30f, -1e30f, -1e30f);
    for (int i = start + lane; i < end; i += 64) {
        float4 s = *(const float4*)&sc1[(size_t)i * 4];
        m.x = fmaxf(m.x, s.x); m.y = fmaxf(m.y, s.y);
        m.z = fmaxf(m.z, s.z); m.w = fmaxf(m.w, s.w);
    }
    #pragma unroll
    for (int off = 32; off; off >>= 1) {
        m.x = fmaxf(m.x, __shfl_xor(m.x, off));
        m.y = fmaxf(m.y, __shfl_xor(m.y, off));
        m.z = fmaxf(m.z, __shfl_xor(m.z, off));
        m.w = fmaxf(m.w, __shfl_xor(m.w, off));
    }
    float4 z = make_float4(0.f, 0.f, 0.f, 0.f);
    for (int i = start + lane; i < end; i += 64) {
        float4 s = *(const float4*)&sc1[(size_t)i * 4];
        z.x += __expf(s.x - m.x); z.y += __expf(s.y - m.y);
        z.z += __expf(s.z - m.z); z.w += __expf(s.w - m.w);
    }
    #pragma unroll
    for (int off = 32; off; off >>= 1) {
        z.x += __shfl_xor(z.x, off); z.y += __shfl_xor(z.y, off);
        z.z += __shfl_xor(z.z, off); z.w += __shfl_xor(z.w, off);
    }
    float4 iz;
    iz.x = 1.f / (z.x + 1e-16f); iz.y = 1.f / (z.y + 1e-16f);
    iz.z = 1.f / (z.z + 1e-16f); iz.w = 1.f / (z.w + 1e-16f);
    if (lane == 0) {
        *(float4*)&mz1[(size_t)n * 8]     = m;
        *(float4*)&mz1[(size_t)n * 8 + 4] = iz;
    }
    // fused alpha1 write (all lanes hold m/iz after butterfly)
    for (int i = start + lane; i < end; i += 64) {
        float4 s = *(const float4*)&sc1[(size_t)i * 4];
        float4 a;
        a.x = __expf(s.x - m.x) * iz.x;
        a.y = __expf(s.y - m.y) * iz.y;
        a.z = __expf(s.z - m.z) * iz.z;
        a.w = __expf(s.w - m.w) * iz.w;
        *(float4*)&alpha_out[(size_t)csr_eid[i] * 4] = a;
    }
}

// ===== node-parallel m,1/z for layer 2: mz2[n] = [m | invz] =====
__global__ __launch_bounds__(256)
void mz2_kernel(const float* __restrict__ sc2, const int* __restrict__ row_ptr,
                float* __restrict__ mz2)
{
    const int n = blockIdx.x * 4 + (threadIdx.x >> 6);
    if (n >= NN) return;
    const int lane = threadIdx.x & 63;
    const int start = row_ptr[n], end = row_ptr[n + 1];
    float m = -1e30f;
    for (int i = start + lane; i < end; i += 64) m = fmaxf(m, sc2[i]);
    #pragma unroll
    for (int off = 32; off; off >>= 1) m = fmaxf(m, __shfl_xor(m, off));
    float z = 0.f;
    for (int i = start + lane; i < end; i += 64) z += __expf(sc2[i] - m);
    #pragma unroll
    for (int off = 32; off; off >>= 1) z += __shfl_xor(z, off);
    if (lane == 0) {
        mz2[(size_t)n * 2]     = m;
        mz2[(size_t)n * 2 + 1] = 1.f / (z + 1e-16f);
    }
}

// ======== layer-1 cooperative px gather — SINGLE PHASE (alpha inline from mz1) ========
__global__ __launch_bounds__(256)
void px_gather(const float* __restrict__ x, const float* __restrict__ sc1,
               const float* __restrict__ mz1, const int* __restrict__ row_ptr,
               const int* __restrict__ csr_src, unsigned short* __restrict__ Apx)
{
    __shared__ float red[4][16][33];
    const int n = blockIdx.x;
    const int t = threadIdx.x;
    const int w = t >> 6;
    const int lane = t & 63;
    const int start = row_ptr[n], end = row_ptr[n + 1];
    const float4 m  = *(const float4*)&mz1[(size_t)n * 8];
    const float4 iz = *(const float4*)&mz1[(size_t)n * 8 + 4];

    const int slot = w * 4 + (lane >> 4);
    const int g = lane & 15;
    float acc[4][8] = {};
    for (int i = start + slot; i < end; i += 16) {
        const int s = csr_src[i];
        float4 sv = *(const float4*)&sc1[(size_t)i * 4];
        const float a0 = __expf(sv.x - m.x) * iz.x;
        const float a1 = __expf(sv.y - m.y) * iz.y;
        const float a2 = __expf(sv.z - m.z) * iz.z;
        const float a3 = __expf(sv.w - m.w) * iz.w;
        const float* xr = &x[(size_t)s * FIN + g * 8];
        float4 v0 = *(const float4*)&xr[0];
        float4 v1 = *(const float4*)&xr[4];
        float vv[8] = { v0.x, v0.y, v0.z, v0.w, v1.x, v1.y, v1.z, v1.w };
        #pragma unroll
        for (int d = 0; d < 8; ++d) {
            acc[0][d] += a0 * vv[d];
            acc[1][d] += a1 * vv[d];
            acc[2][d] += a2 * vv[d];
            acc[3][d] += a3 * vv[d];
        }
    }
    #pragma unroll
    for (int off = 16; off <= 32; off <<= 1)
        #pragma unroll
        for (int h = 0; h < 4; ++h)
            #pragma unroll
            for (int d = 0; d < 8; ++d)
                acc[h][d] += __shfl_xor(acc[h][d], off);
    if ((lane >> 4) == 0) {
        #pragma unroll
        for (int h = 0; h < 4; ++h)
            #pragma unroll
            for (int d = 0; d < 8; ++d)
                red[w][g][h * 8 + d] = acc[h][d];
    }
    __syncthreads();
    if (lane < 16) {
        float sum[8];
        #pragma unroll
        for (int d = 0; d < 8; ++d)
            sum[d] = red[0][lane][w * 8 + d] + red[1][lane][w * 8 + d]
                   + red[2][lane][w * 8 + d] + red[3][lane][w * 8 + d];
        ushort4 hi0, hi1, lo0, lo1;
        split1(sum[0], hi0.x, lo0.x); split1(sum[1], hi0.y, lo0.y);
        split1(sum[2], hi0.z, lo0.z); split1(sum[3], hi0.w, lo0.w);
        split1(sum[4], hi1.x, lo1.x); split1(sum[5], hi1.y, lo1.y);
        split1(sum[6], hi1.z, lo1.z); split1(sum[7], hi1.w, lo1.w);
        unsigned short* orow = Apx + (size_t)n * 1024 + w * 256 + lane * 8;
        *(ushort4*)&orow[0]       = hi0;
        *(ushort4*)&orow[4]       = hi1;
        *(ushort4*)&orow[128]     = lo0;
        *(ushort4*)&orow[132]     = lo1;
    }
}

// ======== layer-2 aggregate — barrier-free, alpha inline from mz2 ========
__global__ __launch_bounds__(64)
void aggregate2(const unsigned short* __restrict__ h2b, const float* __restrict__ sc2,
                const float* __restrict__ mz2, const int* __restrict__ row_ptr,
                const int* __restrict__ csr_src, const float* __restrict__ accin,
                float* __restrict__ out)
{
    const int n = blockIdx.x;
    const int t = threadIdx.x;
    const int start = row_ptr[n], end = row_ptr[n + 1];
    const float m    = mz2[(size_t)n * 2];
    const float invz = mz2[(size_t)n * 2 + 1];

    const int slot = t >> 4, g = t & 15;
    float acc[16] = {};
    for (int i = start + slot; i < end; i += 4) {
        const float a = __expf(sc2[i] - m) * invz;
        const unsigned short* vr = &h2b[(size_t)csr_src[i] * D2 + g * 16];
        bf16x8 u0 = *(const bf16x8*)&vr[0];
        bf16x8 u1 = *(const bf16x8*)&vr[8];
        #pragma unroll
        for (int d = 0; d < 8; ++d) {
            acc[d]     += a * b2f((unsigned short)u0[d]);
            acc[8 + d] += a * b2f((unsigned short)u1[d]);
        }
    }
    #pragma unroll
    for (int off = 16; off <= 32; off <<= 1)
        #pragma unroll
        for (int d = 0; d < 16; ++d)
            acc[d] += __shfl_xor(acc[d], off);
    if (slot == 0) {
        const float* br = &accin[(size_t)n * D2 + g * 16];
        float* orow = &out[(size_t)n * D2 + g * 16];
        #pragma unroll
        for (int q = 0; q < 4; ++q) {
            float4 b = *(const float4*)&br[q * 4];
            float4 r;
            r.x = acc[q * 4 + 0] + b.x; r.y = acc[q * 4 + 1] + b.y;
            r.z = acc[q * 4 + 2] + b.z; r.w = acc[q * 4 + 3] + b.w;
            *(float4*)&orow[q * 4] = r;
        }
    }
}

extern "C" void kernel_launch(void* const* d_in, const int* in_sizes, int n_in,
                              void* d_out, int out_size, void* d_ws, size_t ws_size,
                              hipStream_t stream)
{
    const float* x        = (const float*)d_in[0];
    const int*   ei       = (const int*)  d_in[1];
    const float* W1       = (const float*)d_in[2];
    const float* att_src1 = (const float*)d_in[3];
    const float* att_dst1 = (const float*)d_in[4];
    const float* b1       = (const float*)d_in[5];
    const float* lin1_W   = (const float*)d_in[6];
    const float* lin1_b   = (const float*)d_in[7];
    const float* W2       = (const float*)d_in[8];
    const float* att_src2 = (const float*)d_in[9];
    const float* att_dst2 = (const float*)d_in[10];
    const float* b2       = (const float*)d_in[11];
    const float* lin2_W   = (const float*)d_in[12];
    const float* lin2_b   = (const float*)d_in[13];
    const int* srcp = ei;
    const int* dstp = ei + EE;

    float* out    = (float*)d_out;
    float* alpha1 = out + (size_t)NN * D2;           // [ETOT,4] region of d_out

    float* fw = (float*)d_ws;
    unsigned short* A1stk = (unsigned short*)fw; fw += (size_t)NN * 256 / 2;   // [NN][xhi|xlo]
    unsigned short* Apx   = (unsigned short*)fw; fw += (size_t)NN * 1024 / 2;  // [NN][4][pxhi|pxlo]
    unsigned short* A2stk = (unsigned short*)fw; fw += (size_t)NN * 2048 / 2;  // [NN][h1hi|h1lo]
    unsigned short* h2b   = (unsigned short*)fw; fw += (size_t)NN * 256 / 2;   // [NN][D2] bf16
    float* acc2   = fw;  fw += (size_t)NN * D2;                                 // lin2 residual
    unsigned short* Bt1 = (unsigned short*)fw; fw += (size_t)1024 * 768 / 2;   // [1024][768]
    unsigned short* Bt2 = (unsigned short*)fw; fw += (size_t)512 * 3072 / 2;   // [512][3072]
    float* w1s = fw; fw += 512;
    float* w1d = fw; fw += 512;
    float* v2s = fw; fw += 1024;
    float* v2d = fw; fw += 1024;
    float* s_src1 = fw; fw += NN * NH1;
    float* s_dst1 = fw; fw += NN * NH1;
    float* s_src2 = fw; fw += NN;
    float* s_dst2 = fw; fw += NN;
    float* sc1    = fw; fw += (size_t)ETOT * NH1;   // [ETOT][4] post-lrelu scores, CSR order
    float* sc2    = fw; fw += ETOT;                 // [ETOT]    post-lrelu scores, CSR order
    float* mz1    = fw; fw += (size_t)NN * 8;       // per-node [m x4 | invz x4]
    float* mz2    = fw; fw += (size_t)NN * 2;       // per-node [m | invz]
    int* ip      = (int*)fw;
    int* cnt     = ip;  ip += NN;
    int* fill    = ip;  ip += NN;
    int* row_ptr = ip;  ip += NN + 4;
    int* csr_src = ip;  ip += ETOT;
    int* csr_eid = ip;  ip += ETOT;
    int* csr_dst = ip;  ip += ETOT;

    hipMemsetAsync(cnt, 0, 2 * NN * sizeof(int), stream);

    // ---- fused prep ----
    prep<<<3451, 256, 0, stream>>>(x, A1stk, W1, lin1_W, Bt1, W2, lin2_W, Bt2,
                                   dstp, cnt, att_src1, att_dst1, w1s, w1d,
                                   att_src2, att_dst2, v2s, v2d);

    // ---- layer-1 node scores (projected, f32) ----
    s1_scores<<<(NN + 3) / 4, 256, 0, stream>>>(x, w1s, w1d, s_src1, s_dst1);

    // ---- CSR chain (+ edge-parallel sc1 precompute inside scatter) ----
    scan_kernel<<<1, 1024, 0, stream>>>(cnt, row_ptr);
    scatter_edges<<<(ETOT + 255) / 256, 256, 0, stream>>>(srcp, dstp, row_ptr, fill,
                                                          csr_src, csr_eid, csr_dst,
                                                          s_src1, s_dst1, sc1);

    // ---- layer-1 softmax stats + fused alpha1 write ----
    mz1_alpha<<<(NN + 3) / 4, 256, 0, stream>>>(sc1, row_ptr, csr_eid, mz1, alpha1);

    // ---- layer-1 single-phase cooperative 128-dim gather ----
    px_gather<<<NN, 256, 0, stream>>>(x, sc1, mz1, row_ptr, csr_src, Apx);

    // ---- layer-1 GEMM: [px_h|x] @ [W1_h; lin1W] + biases, ELU, split -> A2stk ----
    gemm_l1<<<79 * 8, 256, 0, stream>>>(Apx, A1stk, Bt1, A2stk, NN, lin1_b, b1);

    // ---- layer-2 node scores + edge-parallel sc2 + node-parallel mz2 ----
    scores2<<<(NN + 3) / 4, 256, 0, stream>>>(A2stk, v2s, v2d, s_src2, s_dst2);
    sc2_kernel<<<(ETOT + 255) / 256, 256, 0, stream>>>(csr_src, csr_dst, s_src2, s_dst2, sc2);
    mz2_kernel<<<(NN + 3) / 4, 256, 0, stream>>>(sc2, row_ptr, mz2);

    // ---- layer-2 GEMM (fused W2|lin2_W), BM=64 BK=64 -> 1256 blocks for occupancy ----
    gemm_split<64, 64, 2, 2, 64><<<157 * 8, 256, 0, stream>>>(
        A2stk, 2 * C1, 2 * C1, Bt2, 3 * C1, h2b, acc2, NN, D2, D2, 8, lin2_b, b2);

    // ---- layer-2 barrier-free aggregate -> out ----
    aggregate2<<<NN, 64, 0, stream>>>(h2b, sc2, mz2, row_ptr, csr_src, acc2, out);
}

// Round 16
// 218.650 us; speedup vs baseline: 1.1379x; 1.1379x over previous
//
#include <hip/hip_runtime.h>
#include <hip/hip_bf16.h>
#include <math.h>

#define NN   10000
#define EE   160000
#define ETOT 170000
#define FIN  128
#define C1   1024   // H1*D1
#define NH1  4
#define D1   256
#define D2   256
#define MAXD 96     // LDS alpha cache depth; fallback recompute guards deg>96

typedef __attribute__((ext_vector_type(8))) short bf16x8;
typedef __attribute__((ext_vector_type(4))) float f32x4;

// ---------------- bf16 helpers ----------------
__device__ __forceinline__ float b2f(unsigned short u)
{
    union { unsigned int i; float f; } c; c.i = (unsigned int)u << 16; return c.f;
}
__device__ __forceinline__ unsigned short f2b(float x)
{
    return __builtin_bit_cast(unsigned short, __float2bfloat16(x));
}
__device__ __forceinline__ void split1(float x, unsigned short &h, unsigned short &l)
{
    __hip_bfloat16 hb = __float2bfloat16(x);
    float r = x - __bfloat162float(hb);
    h = __builtin_bit_cast(unsigned short, hb);
    l = __builtin_bit_cast(unsigned short, __float2bfloat16(r));
}

// ================= fused prep =================
// ranges: [0,1250) split_A(x) ; [1250,1506) Bt1 stack ; [1506,2018) Bt2 ;
//         [2018,2683) count_deg ; [2683,2939) proj1 ; [2939,3451) proj2
__device__ __forceinline__ void split_A_body(const float* __restrict__ X,
                                             unsigned short* __restrict__ A2,
                                             int M, int K, int idx)
{
    int kq4 = K >> 2;
    if (idx >= M * kq4) return;
    int m = idx / kq4, kq = idx % kq4;
    float4 v = *(const float4*)&X[(size_t)m * K + kq * 4];
    ushort4 h, l;
    split1(v.x, h.x, l.x); split1(v.y, h.y, l.y);
    split1(v.z, h.z, l.z); split1(v.w, h.w, l.w);
    unsigned short* row = A2 + (size_t)m * (2 * K);
    *(ushort4*)&row[kq * 4]     = h;
    *(ushort4*)&row[K + kq * 4] = l;
}

__device__ __forceinline__ void split_Bt_body(const float* __restrict__ B0,
                                              const float* __restrict__ B1,
                                              int K, int N0, int Ntot,
                                              unsigned short* __restrict__ Bt, int idx)
{
    int total = Ntot * (K >> 2);
    if (idx >= total) return;
    int n = idx % Ntot;
    int kq = idx / Ntot;
    int k = kq * 4;
    const float* B; int nc, nb;
    if (n < N0) { B = B0; nc = n; nb = N0; }
    else        { B = B1; nc = n - N0; nb = Ntot - N0; }
    float v0 = B[(size_t)(k + 0) * nb + nc];
    float v1 = B[(size_t)(k + 1) * nb + nc];
    float v2 = B[(size_t)(k + 2) * nb + nc];
    float v3 = B[(size_t)(k + 3) * nb + nc];
    ushort4 h, l;
    split1(v0, h.x, l.x); split1(v1, h.y, l.y);
    split1(v2, h.z, l.z); split1(v3, h.w, l.w);
    unsigned short* row = Bt + (size_t)n * (3 * K);
    *(ushort4*)&row[k]         = h;
    *(ushort4*)&row[K + k]     = h;
    *(ushort4*)&row[2 * K + k] = l;
}

// Bt1: stacked [W1; lin1W] (K=256, N=1024) -> rows [bhi(256)|bhi(256)|blo(256)]
__device__ __forceinline__ void split_Bt1_body(const float* __restrict__ W1,
                                               const float* __restrict__ lin1W,
                                               unsigned short* __restrict__ Bt, int idx)
{
    if (idx >= 1024 * 64) return;
    int n = idx & 1023;
    int k = (idx >> 10) * 4;     // 0..252
    float v[4];
    #pragma unroll
    for (int i = 0; i < 4; ++i) {
        int kk = k + i;
        v[i] = (kk < 128) ? W1[(size_t)kk * C1 + n] : lin1W[(size_t)(kk - 128) * C1 + n];
    }
    ushort4 h, l;
    split1(v[0], h.x, l.x); split1(v[1], h.y, l.y);
    split1(v[2], h.z, l.z); split1(v[3], h.w, l.w);
    unsigned short* row = Bt + (size_t)n * 768;
    *(ushort4*)&row[k]       = h;
    *(ushort4*)&row[256 + k] = h;
    *(ushort4*)&row[512 + k] = l;
}

__global__ __launch_bounds__(256)
void prep(const float* __restrict__ x, unsigned short* __restrict__ A1stk,
          const float* __restrict__ W1, const float* __restrict__ lin1_W,
          unsigned short* __restrict__ Bt1,
          const float* __restrict__ W2, const float* __restrict__ lin2_W,
          unsigned short* __restrict__ Bt2,
          const int* __restrict__ dstp, int* __restrict__ cnt,
          const float* __restrict__ as1, const float* __restrict__ ad1,
          float* __restrict__ w1s, float* __restrict__ w1d,
          const float* __restrict__ as2, const float* __restrict__ ad2,
          float* __restrict__ v2s, float* __restrict__ v2d)
{
    const int b = blockIdx.x, t = threadIdx.x;
    const int w = t >> 6, lane = t & 63;
    if (b < 1250) {
        split_A_body(x, A1stk, NN, FIN, b * 256 + t);
    } else if (b < 1506) {
        split_Bt1_body(W1, lin1_W, Bt1, (b - 1250) * 256 + t);
    } else if (b < 2018) {
        split_Bt_body(W2, lin2_W, C1, D2, 512, Bt2, (b - 1506) * 256 + t);
    } else if (b < 2683) {
        int e = (b - 2018) * 256 + t;
        if (e < ETOT) {
            int d = (e < EE) ? dstp[e] : (e - EE);
            atomicAdd(&cnt[d], 1);
        }
    } else if (b < 2939) {
        int gw = (b - 2683) * 4 + w;
        int k = gw >> 3, rem = gw & 7, h = rem >> 1, issd = rem & 1;
        const float* a = issd ? ad1 : as1;
        float4 wv = *(const float4*)&W1[(size_t)k * C1 + h * 256 + lane * 4];
        float4 av = *(const float4*)&a[h * 256 + lane * 4];
        float s = wv.x * av.x + wv.y * av.y + wv.z * av.z + wv.w * av.w;
        #pragma unroll
        for (int off = 32; off; off >>= 1) s += __shfl_xor(s, off);
        if (lane == 0) (issd ? w1d : w1s)[k * 4 + h] = s;
    } else {
        int gw = (b - 2939) * 4 + w;
        int k = gw >> 1, issd = gw & 1;
        const float* a = issd ? ad2 : as2;
        float4 wv = *(const float4*)&W2[(size_t)k * D2 + lane * 4];
        float4 av = *(const float4*)&a[lane * 4];
        float s = wv.x * av.x + wv.y * av.y + wv.z * av.z + wv.w * av.w;
        #pragma unroll
        for (int off = 32; off; off >>= 1) s += __shfl_xor(s, off);
        if (lane == 0) (issd ? v2d : v2s)[k] = s;
    }
}

// ================= GEMMs =================
__device__ __forceinline__ void glds16(const void* g, void* l)
{
    __builtin_amdgcn_global_load_lds((const __attribute__((address_space(1))) void*)g,
                                     (__attribute__((address_space(3))) void*)l, 16, 0, 0);
}

// ---- layer-1 GEMM: per-head A = [px_h | x] split-bf16, keff=768, out = ELU(.)+biases
__global__ __launch_bounds__(256)
void gemm_l1(const unsigned short* __restrict__ Apx,   // [NN][4*256] per-head [hi128|lo128]
             const unsigned short* __restrict__ Ax,    // [NN][256]  [xhi|xlo]
             const unsigned short* __restrict__ Bt,    // [1024][768]
             unsigned short* __restrict__ h1split,     // [NN][2048] [hi1024|lo1024]
             int M, const float* __restrict__ bias0, const float* __restrict__ bias1)
{
    constexpr int BM = 128, BN = 128, BK = 32;
    constexpr int FJ = 4, FI = 4;
    constexpr int SLOTS = 4, SMASK = 3, SWSH = 1;
    constexpr int RPC = 16, ACH = 8, CPW = 4;
    constexpr int ABUF = BM * BK, BBUF = BN * BK;
    __shared__ __align__(16) unsigned short sA[2 * ABUF];
    __shared__ __align__(16) unsigned short sB[2 * BBUF];
    const int tid = threadIdx.x, w = tid >> 6, lane = tid & 63;
    const int cpx = gridDim.x >> 3;
    const int t0 = (blockIdx.x & 7) * cpx + (blockIdx.x >> 3);
    const int m0 = (t0 >> 3) * BM;          // ntn = 8
    const int n0 = (t0 & 7) * BN;
    const int hsel = n0 >> 8;               // head
    const int wm = w >> 1, wn = w & 1;
    f32x4 acc[FI][FJ] = {};

    const unsigned short *gx[CPW], *gpx[CPW], *gb[CPW];
    int lofs[CPW]; bool isa[CPW];
    {
        const int r = lane / SLOTS, sl = lane % SLOTS;
        const int ssl = sl ^ ((r >> SWSH) & SMASK);
        #pragma unroll
        for (int cc = 0; cc < CPW; ++cc) {
            int c = w * CPW + cc;
            if (c < ACH) {
                int gm = m0 + c * RPC + r; if (gm >= M) gm = M - 1;
                gx[cc]  = Ax  + (size_t)gm * 256 + ssl * 8;
                gpx[cc] = Apx + (size_t)gm * 1024 + hsel * 256 + ssl * 8;
                gb[cc]  = nullptr;
                lofs[cc] = c * 512;
                isa[cc] = true;
            } else {
                int gn = n0 + (c - ACH) * RPC + r;
                gx[cc] = gpx[cc] = nullptr;
                gb[cc] = Bt + (size_t)gn * 768 + ssl * 8;
                lofs[cc] = (c - ACH) * 512;
                isa[cc] = false;
            }
        }
    }

    const int rAl = wm * 64 + (lane & 15);
    const int rBl = wn * 64 + (lane & 15);
    const int sIdx = lane >> 4;
    const int nit = 768 / BK;               // 24
    int cur = 0;

    auto stage = [&](int kk, int buf) {
        int rr = kk >> 7;                   // 0..5
        bool px = !(rr & 1);
        int off = px ? ((rr == 2) ? 128 : 0) : ((rr == 3) ? 128 : 0);
        int kin = kk & 127;
        #pragma unroll
        for (int cc = 0; cc < CPW; ++cc) {
            if (isa[cc]) glds16((px ? gpx[cc] : gx[cc]) + off + kin, sA + buf * ABUF + lofs[cc]);
            else         glds16(gb[cc] + kk,                         sB + buf * BBUF + lofs[cc]);
        }
    };

    stage(0, 0);
    __syncthreads();
    for (int it = 0; it < nit; ++it) {
        if (it + 1 < nit) stage((it + 1) * BK, cur ^ 1);
        const unsigned short* cA = sA + cur * ABUF;
        const unsigned short* cB = sB + cur * BBUF;
        bf16x8 av[FJ], bv[FI];
        #pragma unroll
        for (int f = 0; f < FI; ++f) {
            int row = rBl + f * 16;
            bv[f] = *(const bf16x8*)&cB[row * BK + ((sIdx ^ ((row >> SWSH) & SMASK)) << 3)];
        }
        #pragma unroll
        for (int f = 0; f < FJ; ++f) {
            int row = rAl + f * 16;
            av[f] = *(const bf16x8*)&cA[row * BK + ((sIdx ^ ((row >> SWSH) & SMASK)) << 3)];
        }
        #pragma unroll
        for (int fj = 0; fj < FJ; ++fj)
            #pragma unroll
            for (int fi = 0; fi < FI; ++fi)
                acc[fi][fj] = __builtin_amdgcn_mfma_f32_16x16x32_bf16(
                    bv[fi], av[fj], acc[fi][fj], 0, 0, 0);
        __syncthreads();
        cur ^= 1;
    }

    const int lrow = lane & 15;
    const int lcol = (lane >> 4) << 2;
    #pragma unroll
    for (int fj = 0; fj < FJ; ++fj) {
        int row = m0 + wm * 64 + fj * 16 + lrow;
        if (row >= M) continue;
        #pragma unroll
        for (int fi = 0; fi < FI; ++fi) {
            int col = n0 + wn * 64 + fi * 16 + lcol;
            f32x4 v = acc[fi][fj];
            const float4 g0 = *(const float4*)&bias0[col];
            const float4 g1 = *(const float4*)&bias1[col];
            v[0] += g0.x + g1.x; v[1] += g0.y + g1.y;
            v[2] += g0.z + g1.z; v[3] += g0.w + g1.w;
            #pragma unroll
            for (int i = 0; i < 4; ++i) v[i] = v[i] > 0.f ? v[i] : expm1f(v[i]);
            ushort4 hi, lo;
            split1(v[0], hi.x, lo.x); split1(v[1], hi.y, lo.y);
            split1(v[2], hi.z, lo.z); split1(v[3], hi.w, lo.w);
            unsigned short* orow = h1split + (size_t)row * 2048;
            *(ushort4*)&orow[col]        = hi;
            *(ushort4*)&orow[C1 + col]   = lo;
        }
    }
}

// ---- generic split-bf16 GEMM (layer 2), BM templated ----
template<int BM, int BN, int WM, int WN, int BK>
__global__ __launch_bounds__(256)
void gemm_split(const unsigned short* __restrict__ A, int lda, int ka2,
                const unsigned short* __restrict__ Bt, int keff,
                unsigned short* __restrict__ outPb, float* __restrict__ outR,
                int M, int nsplit, int ldR, int ntn,
                const float* __restrict__ bias0, const float* __restrict__ bias1)
{
    constexpr int WTM  = BM / WM,  WTN = BN / WN;
    constexpr int FJ   = WTM / 16, FI  = WTN / 16;
    constexpr int KS   = BK / 32;
    constexpr int SLOTS = BK / 8;
    constexpr int SMASK = SLOTS - 1;
    constexpr int SWSH  = (BK == 32) ? 1 : 0;
    constexpr int RPC  = 512 / BK;
    constexpr int ACH  = BM / RPC;
    constexpr int NCH  = (BM + BN) / RPC;
    constexpr int CPW  = NCH / 4;
    constexpr int ABUF = BM * BK, BBUF = BN * BK;

    __shared__ __align__(16) unsigned short sA[2 * ABUF];
    __shared__ __align__(16) unsigned short sB[2 * BBUF];

    const int tid = threadIdx.x;
    const int w = tid >> 6, lane = tid & 63;

    const int cpx = gridDim.x >> 3;
    const int t0  = (blockIdx.x & 7) * cpx + (blockIdx.x >> 3);
    const int m0 = (t0 / ntn) * BM;
    const int n0 = (t0 % ntn) * BN;
    const int wm = w / WN, wn = w % WN;

    f32x4 acc[FI][FJ] = {};

    const unsigned short* gp[CPW];
    int lofs[CPW];
    bool isa[CPW];
    {
        const int r  = lane / SLOTS;
        const int sl = lane % SLOTS;
        const int ssl = sl ^ ((r >> SWSH) & SMASK);
        #pragma unroll
        for (int cc = 0; cc < CPW; ++cc) {
            int c = w * CPW + cc;
            if (c < ACH) {
                int gm = m0 + c * RPC + r; if (gm >= M) gm = M - 1;
                gp[cc]   = A + (size_t)gm * lda + ssl * 8;
                lofs[cc] = c * 512;
                isa[cc]  = true;
            } else {
                int gn = n0 + (c - ACH) * RPC + r;
                gp[cc]   = Bt + (size_t)gn * keff + ssl * 8;
                lofs[cc] = (c - ACH) * 512;
                isa[cc]  = false;
            }
        }
    }

    const int rAl = wm * WTM + (lane & 15);
    const int rBl = wn * WTN + (lane & 15);
    const int koff = (lane >> 4) * 8;
    const int nit = keff / BK;
    int cur = 0;

    #pragma unroll
    for (int cc = 0; cc < CPW; ++cc)
        glds16(gp[cc], (isa[cc] ? sA : sB) + lofs[cc]);
    __syncthreads();

    for (int it = 0; it < nit; ++it) {
        if (it + 1 < nit) {
            int kn = (it + 1) * BK;
            int kAn = (kn >= ka2) ? (kn - ka2) : kn;
            #pragma unroll
            for (int cc = 0; cc < CPW; ++cc) {
                unsigned short* dst = (isa[cc] ? sA + (cur ^ 1) * ABUF
                                               : sB + (cur ^ 1) * BBUF) + lofs[cc];
                glds16(gp[cc] + (isa[cc] ? kAn : kn), dst);
            }
        }
        const unsigned short* cA = sA + cur * ABUF;
        const unsigned short* cB = sB + cur * BBUF;
        #pragma unroll
        for (int ks = 0; ks < KS; ++ks) {
            const int sIdx = (ks * 32 + koff) >> 3;
            bf16x8 av[FJ], bv[FI];
            #pragma unroll
            for (int f = 0; f < FI; ++f) {
                int row = rBl + f * 16;
                bv[f] = *(const bf16x8*)&cB[row * BK + ((sIdx ^ ((row >> SWSH) & SMASK)) << 3)];
            }
            #pragma unroll
            for (int f = 0; f < FJ; ++f) {
                int row = rAl + f * 16;
                av[f] = *(const bf16x8*)&cA[row * BK + ((sIdx ^ ((row >> SWSH) & SMASK)) << 3)];
            }
            #pragma unroll
            for (int fj = 0; fj < FJ; ++fj)
                #pragma unroll
                for (int fi = 0; fi < FI; ++fi)
                    acc[fi][fj] = __builtin_amdgcn_mfma_f32_16x16x32_bf16(
                        bv[fi], av[fj], acc[fi][fj], 0, 0, 0);
        }
        __syncthreads();
        cur ^= 1;
    }

    const int lrow = lane & 15;
    const int lcol = (lane >> 4) << 2;
    #pragma unroll
    for (int fj = 0; fj < FJ; ++fj) {
        int row = m0 + wm * WTM + fj * 16 + lrow;
        if (row >= M) continue;
        #pragma unroll
        for (int fi = 0; fi < FI; ++fi) {
            int col = n0 + wn * WTN + fi * 16 + lcol;
            f32x4 v = acc[fi][fj];
            if (col < nsplit) {
                ushort4 o;
                o.x = f2b(v[0]); o.y = f2b(v[1]); o.z = f2b(v[2]); o.w = f2b(v[3]);
                *(ushort4*)&outPb[(size_t)row * nsplit + col] = o;
            } else {
                int c = col - nsplit;
                const float4 g0 = *(const float4*)&bias0[c];
                const float4 g1 = *(const float4*)&bias1[c];
                v[0] += g0.x + g1.x; v[1] += g0.y + g1.y;
                v[2] += g0.z + g1.z; v[3] += g0.w + g1.w;
                *(f32x4*)&outR[(size_t)row * ldR + c] = v;
            }
        }
    }
}

// ================= scores + scan (fused; both depend only on prep) =================
__global__ __launch_bounds__(256)
void s1_scores_scan(const float* __restrict__ x, const float* __restrict__ w1s,
                    const float* __restrict__ w1d, float* __restrict__ s_src,
                    float* __restrict__ s_dst,
                    const int* __restrict__ cnt, int* __restrict__ row_ptr)
{
    const int b = blockIdx.x;
    if (b < (NN + 3) / 4) {
        const int n = b * 4 + (threadIdx.x >> 6);
        if (n >= NN) return;
        const int lane = threadIdx.x & 63;
        float2 xv = *(const float2*)&x[(size_t)n * FIN + lane * 2];
        float4 wa = *(const float4*)&w1s[(lane * 2) * 4];
        float4 wb = *(const float4*)&w1s[(lane * 2 + 1) * 4];
        float4 da = *(const float4*)&w1d[(lane * 2) * 4];
        float4 db = *(const float4*)&w1d[(lane * 2 + 1) * 4];
        float ss[4] = { xv.x * wa.x + xv.y * wb.x, xv.x * wa.y + xv.y * wb.y,
                        xv.x * wa.z + xv.y * wb.z, xv.x * wa.w + xv.y * wb.w };
        float sd[4] = { xv.x * da.x + xv.y * db.x, xv.x * da.y + xv.y * db.y,
                        xv.x * da.z + xv.y * db.z, xv.x * da.w + xv.y * db.w };
        #pragma unroll
        for (int off = 32; off; off >>= 1) {
            #pragma unroll
            for (int h = 0; h < 4; ++h) {
                ss[h] += __shfl_xor(ss[h], off);
                sd[h] += __shfl_xor(sd[h], off);
            }
        }
        if (lane == 0) {
            #pragma unroll
            for (int h = 0; h < 4; ++h) {
                s_src[n * NH1 + h] = ss[h];
                s_dst[n * NH1 + h] = sd[h];
            }
        }
    } else {
        // exclusive scan of cnt[0..NN) with 256 threads x 40 elements
        __shared__ float partf[256];     // reuse as int via bit_cast-free: use int array
        __shared__ int part[256];
        (void)partf;
        const int t = threadIdx.x;
        int local[40];
        int s = 0;
        #pragma unroll
        for (int j = 0; j < 40; ++j) {
            int idx = t * 40 + j;
            local[j] = s;
            s += (idx < NN) ? cnt[idx] : 0;
        }
        part[t] = s;
        __syncthreads();
        for (int off = 1; off < 256; off <<= 1) {
            int v = (t >= off) ? part[t - off] : 0;
            __syncthreads();
            part[t] += v;
            __syncthreads();
        }
        int prefix = (t > 0) ? part[t - 1] : 0;
        #pragma unroll
        for (int j = 0; j < 40; ++j) {
            int idx = t * 40 + j;
            if (idx < NN) row_ptr[idx] = prefix + local[j];
        }
        if (t == 0) row_ptr[NN] = ETOT;
    }
}

// ================= CSR scatter =================
__global__ void scatter_edges(const int* __restrict__ srcp, const int* __restrict__ dstp,
                              const int* __restrict__ row_ptr, int* __restrict__ fill,
                              int* __restrict__ csr_src, int* __restrict__ csr_eid)
{
    int e = blockIdx.x * 256 + threadIdx.x;
    if (e >= ETOT) return;
    int s, d;
    if (e < EE) { s = srcp[e]; d = dstp[e]; } else { s = d = e - EE; }
    int pos = row_ptr[d] + atomicAdd(&fill[d], 1);
    csr_src[pos] = s;
    csr_eid[pos] = e;
}

// ================= layer-1 softmax + cooperative 128-dim px gather (r10) =============
__global__ __launch_bounds__(256)
void px_gather(const float* __restrict__ x, const float* __restrict__ s_src,
               const float* __restrict__ s_dst, const int* __restrict__ row_ptr,
               const int* __restrict__ csr_src, const int* __restrict__ csr_eid,
               unsigned short* __restrict__ Apx, float* __restrict__ alpha_out)
{
    __shared__ float lalpha[NH1][MAXD];
    __shared__ float lmz[NH1][2];
    __shared__ float red[4][16][33];
    const int n = blockIdx.x;
    const int t = threadIdx.x;
    const int w = t >> 6;
    const int lane = t & 63;
    const int start = row_ptr[n], end = row_ptr[n + 1];

    // phase 1: wave w = head w softmax (3-pass, scattered reads)
    {
        const int h = w;
        const float sd = s_dst[n * NH1 + h];
        float m = -1e30f;
        for (int i = start + lane; i < end; i += 64) {
            float sc = s_src[csr_src[i] * NH1 + h] + sd;
            sc = sc > 0.f ? sc : 0.2f * sc;
            m = fmaxf(m, sc);
        }
        #pragma unroll
        for (int off = 32; off; off >>= 1) m = fmaxf(m, __shfl_xor(m, off));
        float z = 0.f;
        for (int i = start + lane; i < end; i += 64) {
            float sc = s_src[csr_src[i] * NH1 + h] + sd;
            sc = sc > 0.f ? sc : 0.2f * sc;
            z += __expf(sc - m);
        }
        #pragma unroll
        for (int off = 32; off; off >>= 1) z += __shfl_xor(z, off);
        const float invz = 1.f / (z + 1e-16f);
        for (int i = start + lane; i < end; i += 64) {
            float sc = s_src[csr_src[i] * NH1 + h] + sd;
            sc = sc > 0.f ? sc : 0.2f * sc;
            float a = __expf(sc - m) * invz;
            alpha_out[(size_t)csr_eid[i] * NH1 + h] = a;
            int idx = i - start;
            if (idx < MAXD) lalpha[h][idx] = a;
        }
        if (lane == 0) { lmz[h][0] = m; lmz[h][1] = invz; }
    }
    __syncthreads();

    // phase 2: cooperative gather: 16 edge-slots x 16 dim-groups x 8 f32 dims
    const int slot = w * 4 + (lane >> 4);
    const int g = lane & 15;
    float a0, a1, a2, a3;
    float acc[4][8] = {};
    for (int i = start + slot; i < end; i += 16) {
        const int s = csr_src[i];
        const int idx = i - start;
        if (idx < MAXD) {
            a0 = lalpha[0][idx]; a1 = lalpha[1][idx];
            a2 = lalpha[2][idx]; a3 = lalpha[3][idx];
        } else {
            #pragma unroll
            for (int h = 0; h < 4; ++h) {
                float sc = s_src[s * NH1 + h] + s_dst[n * NH1 + h];
                sc = sc > 0.f ? sc : 0.2f * sc;
                float a = __expf(sc - lmz[h][0]) * lmz[h][1];
                if (h == 0) a0 = a; else if (h == 1) a1 = a;
                else if (h == 2) a2 = a; else a3 = a;
            }
        }
        const float* xr = &x[(size_t)s * FIN + g * 8];
        float4 v0 = *(const float4*)&xr[0];
        float4 v1 = *(const float4*)&xr[4];
        float vv[8] = { v0.x, v0.y, v0.z, v0.w, v1.x, v1.y, v1.z, v1.w };
        #pragma unroll
        for (int d = 0; d < 8; ++d) {
            acc[0][d] += a0 * vv[d];
            acc[1][d] += a1 * vv[d];
            acc[2][d] += a2 * vv[d];
            acc[3][d] += a3 * vv[d];
        }
    }
    #pragma unroll
    for (int off = 16; off <= 32; off <<= 1)
        #pragma unroll
        for (int h = 0; h < 4; ++h)
            #pragma unroll
            for (int d = 0; d < 8; ++d)
                acc[h][d] += __shfl_xor(acc[h][d], off);
    if ((lane >> 4) == 0) {
        #pragma unroll
        for (int h = 0; h < 4; ++h)
            #pragma unroll
            for (int d = 0; d < 8; ++d)
                red[w][g][h * 8 + d] = acc[h][d];
    }
    __syncthreads();
    if (lane < 16) {
        float sum[8];
        #pragma unroll
        for (int d = 0; d < 8; ++d)
            sum[d] = red[0][lane][w * 8 + d] + red[1][lane][w * 8 + d]
                   + red[2][lane][w * 8 + d] + red[3][lane][w * 8 + d];
        ushort4 hi0, hi1, lo0, lo1;
        split1(sum[0], hi0.x, lo0.x); split1(sum[1], hi0.y, lo0.y);
        split1(sum[2], hi0.z, lo0.z); split1(sum[3], hi0.w, lo0.w);
        split1(sum[4], hi1.x, lo1.x); split1(sum[5], hi1.y, lo1.y);
        split1(sum[6], hi1.z, lo1.z); split1(sum[7], hi1.w, lo1.w);
        unsigned short* orow = Apx + (size_t)n * 1024 + w * 256 + lane * 8;
        *(ushort4*)&orow[0]       = hi0;
        *(ushort4*)&orow[4]       = hi1;
        *(ushort4*)&orow[128]     = lo0;
        *(ushort4*)&orow[132]     = lo1;
    }
}

// ================= layer-2 scores =================
__global__ __launch_bounds__(256)
void scores2(const unsigned short* __restrict__ h1split, const float* __restrict__ v2s,
             const float* __restrict__ v2d, float* __restrict__ s_src,
             float* __restrict__ s_dst)
{
    const int n = blockIdx.x * 4 + (threadIdx.x >> 6);
    if (n >= NN) return;
    const int lane = threadIdx.x & 63;
    const unsigned short* row = h1split + (size_t)n * 2048 + lane * 16;
    float ss = 0.f, sd = 0.f;
    #pragma unroll
    for (int q = 0; q < 16; ++q) {
        float hv = b2f(row[q]);
        ss += hv * v2s[lane * 16 + q];
        sd += hv * v2d[lane * 16 + q];
    }
    #pragma unroll
    for (int off = 32; off; off >>= 1) {
        ss += __shfl_xor(ss, off);
        sd += __shfl_xor(sd, off);
    }
    if (lane == 0) { s_src[n] = ss; s_dst[n] = sd; }
}

// ====== layer-2 softmax (scattered, LDS alpha) + 4-slot aggregate + residual (r10) =====
__global__ __launch_bounds__(64)
void aggregate2(const unsigned short* __restrict__ h2b, const float* __restrict__ s_src,
                const float* __restrict__ s_dst,
                const int* __restrict__ row_ptr, const int* __restrict__ csr_src,
                const float* __restrict__ accin, float* __restrict__ out)
{
    __shared__ float lalpha[MAXD];
    const int n = blockIdx.x;
    const int t = threadIdx.x;
    const int start = row_ptr[n], end = row_ptr[n + 1];
    const float sd = s_dst[n];

    float m = -1e30f;
    for (int i = start + t; i < end; i += 64) {
        float sc = s_src[csr_src[i]] + sd;
        sc = sc > 0.f ? sc : 0.2f * sc;
        m = fmaxf(m, sc);
    }
    #pragma unroll
    for (int off = 32; off; off >>= 1) m = fmaxf(m, __shfl_xor(m, off));
    float z = 0.f;
    for (int i = start + t; i < end; i += 64) {
        float sc = s_src[csr_src[i]] + sd;
        sc = sc > 0.f ? sc : 0.2f * sc;
        z += __expf(sc - m);
    }
    #pragma unroll
    for (int off = 32; off; off >>= 1) z += __shfl_xor(z, off);
    const float invz = 1.f / (z + 1e-16f);
    for (int i = start + t; i < end; i += 64) {
        float sc = s_src[csr_src[i]] + sd;
        sc = sc > 0.f ? sc : 0.2f * sc;
        int idx = i - start;
        if (idx < MAXD) lalpha[idx] = __expf(sc - m) * invz;
    }
    __syncthreads();

    const int slot = t >> 4, g = t & 15;
    float acc[16] = {};
    for (int i = start + slot; i < end; i += 4) {
        const int s = csr_src[i];
        const int idx = i - start;
        float a;
        if (idx < MAXD) {
            a = lalpha[idx];
        } else {
            float sc = s_src[s] + sd;
            sc = sc > 0.f ? sc : 0.2f * sc;
            a = __expf(sc - m) * invz;
        }
        const unsigned short* vr = &h2b[(size_t)s * D2 + g * 16];
        bf16x8 u0 = *(const bf16x8*)&vr[0];
        bf16x8 u1 = *(const bf16x8*)&vr[8];
        #pragma unroll
        for (int d = 0; d < 8; ++d) {
            acc[d]     += a * b2f((unsigned short)u0[d]);
            acc[8 + d] += a * b2f((unsigned short)u1[d]);
        }
    }
    #pragma unroll
    for (int off = 16; off <= 32; off <<= 1)
        #pragma unroll
        for (int d = 0; d < 16; ++d)
            acc[d] += __shfl_xor(acc[d], off);
    if (slot == 0) {
        const float* br = &accin[(size_t)n * D2 + g * 16];
        float* orow = &out[(size_t)n * D2 + g * 16];
        #pragma unroll
        for (int q = 0; q < 4; ++q) {
            float4 b = *(const float4*)&br[q * 4];
            float4 r;
            r.x = acc[q * 4 + 0] + b.x; r.y = acc[q * 4 + 1] + b.y;
            r.z = acc[q * 4 + 2] + b.z; r.w = acc[q * 4 + 3] + b.w;
            *(float4*)&orow[q * 4] = r;
        }
    }
}

extern "C" void kernel_launch(void* const* d_in, const int* in_sizes, int n_in,
                              void* d_out, int out_size, void* d_ws, size_t ws_size,
                              hipStream_t stream)
{
    const float* x        = (const float*)d_in[0];
    const int*   ei       = (const int*)  d_in[1];
    const float* W1       = (const float*)d_in[2];
    const float* att_src1 = (const float*)d_in[3];
    const float* att_dst1 = (const float*)d_in[4];
    const float* b1       = (const float*)d_in[5];
    const float* lin1_W   = (const float*)d_in[6];
    const float* lin1_b   = (const float*)d_in[7];
    const float* W2       = (const float*)d_in[8];
    const float* att_src2 = (const float*)d_in[9];
    const float* att_dst2 = (const float*)d_in[10];
    const float* b2       = (const float*)d_in[11];
    const float* lin2_W   = (const float*)d_in[12];
    const float* lin2_b   = (const float*)d_in[13];
    const int* srcp = ei;
    const int* dstp = ei + EE;

    float* out    = (float*)d_out;
    float* alpha1 = out + (size_t)NN * D2;           // [ETOT,4] region of d_out

    float* fw = (float*)d_ws;
    unsigned short* A1stk = (unsigned short*)fw; fw += (size_t)NN * 256 / 2;   // [NN][xhi|xlo]
    unsigned short* Apx   = (unsigned short*)fw; fw += (size_t)NN * 1024 / 2;  // [NN][4][pxhi|pxlo]
    unsigned short* A2stk = (unsigned short*)fw; fw += (size_t)NN * 2048 / 2;  // [NN][h1hi|h1lo]
    unsigned short* h2b   = (unsigned short*)fw; fw += (size_t)NN * 256 / 2;   // [NN][D2] bf16
    float* acc2   = fw;  fw += (size_t)NN * D2;                                 // lin2 residual
    unsigned short* Bt1 = (unsigned short*)fw; fw += (size_t)1024 * 768 / 2;   // [1024][768]
    unsigned short* Bt2 = (unsigned short*)fw; fw += (size_t)512 * 3072 / 2;   // [512][3072]
    float* w1s = fw; fw += 512;
    float* w1d = fw; fw += 512;
    float* v2s = fw; fw += 1024;
    float* v2d = fw; fw += 1024;
    float* s_src1 = fw; fw += NN * NH1;
    float* s_dst1 = fw; fw += NN * NH1;
    float* s_src2 = fw; fw += NN;
    float* s_dst2 = fw; fw += NN;
    int* ip      = (int*)fw;
    int* cnt     = ip;  ip += NN;
    int* fill    = ip;  ip += NN;
    int* row_ptr = ip;  ip += NN + 4;
    int* csr_src = ip;  ip += ETOT;
    int* csr_eid = ip;  ip += ETOT;

    hipMemsetAsync(cnt, 0, 2 * NN * sizeof(int), stream);

    // ---- fused prep ----
    prep<<<3451, 256, 0, stream>>>(x, A1stk, W1, lin1_W, Bt1, W2, lin2_W, Bt2,
                                   dstp, cnt, att_src1, att_dst1, w1s, w1d,
                                   att_src2, att_dst2, v2s, v2d);

    // ---- layer-1 node scores + CSR scan (fused; both depend only on prep) ----
    s1_scores_scan<<<(NN + 3) / 4 + 1, 256, 0, stream>>>(x, w1s, w1d, s_src1, s_dst1,
                                                         cnt, row_ptr);

    // ---- CSR scatter ----
    scatter_edges<<<(ETOT + 255) / 256, 256, 0, stream>>>(srcp, dstp, row_ptr, fill,
                                                          csr_src, csr_eid);

    // ---- layer-1 softmax + cooperative 128-dim gather (alpha1 -> d_out) ----
    px_gather<<<NN, 256, 0, stream>>>(x, s_src1, s_dst1, row_ptr, csr_src, csr_eid,
                                      Apx, alpha1);

    // ---- layer-1 GEMM: [px_h|x] @ [W1_h; lin1W] + biases, ELU, split -> A2stk ----
    gemm_l1<<<79 * 8, 256, 0, stream>>>(Apx, A1stk, Bt1, A2stk, NN, lin1_b, b1);

    // ---- layer-2 scores ----
    scores2<<<(NN + 3) / 4, 256, 0, stream>>>(A2stk, v2s, v2d, s_src2, s_dst2);

    // ---- layer-2 GEMM (fused W2|lin2_W), BM=128 BN=64 BK=64 (best measured) ----
    gemm_split<128, 64, 4, 1, 64><<<79 * 8, 256, 0, stream>>>(
        A2stk, 2 * C1, 2 * C1, Bt2, 3 * C1, h2b, acc2, NN, D2, D2, 8, lin2_b, b2);

    // ---- layer-2 softmax + aggregate -> out ----
    aggregate2<<<NN, 64, 0, stream>>>(h2b, s_src2, s_dst2, row_ptr, csr_src, acc2, out);
}

// Round 17
// 218.498 us; speedup vs baseline: 1.1387x; 1.0007x over previous
//
#include <hip/hip_runtime.h>
#include <hip/hip_bf16.h>
#include <math.h>

#define NN   10000
#define EE   160000
#define ETOT 170000
#define FIN  128
#define C1   1024   // H1*D1
#define NH1  4
#define D1   256
#define D2   256
#define MAXD 96     // LDS alpha cache depth; fallback recompute guards deg>96

typedef __attribute__((ext_vector_type(8))) short bf16x8;
typedef __attribute__((ext_vector_type(4))) float f32x4;

// ---------------- bf16 helpers ----------------
__device__ __forceinline__ float b2f(unsigned short u)
{
    union { unsigned int i; float f; } c; c.i = (unsigned int)u << 16; return c.f;
}
__device__ __forceinline__ unsigned short f2b(float x)
{
    return __builtin_bit_cast(unsigned short, __float2bfloat16(x));
}
__device__ __forceinline__ void split1(float x, unsigned short &h, unsigned short &l)
{
    __hip_bfloat16 hb = __float2bfloat16(x);
    float r = x - __bfloat162float(hb);
    h = __builtin_bit_cast(unsigned short, hb);
    l = __builtin_bit_cast(unsigned short, __float2bfloat16(r));
}

// ================= fused prep =================
__device__ __forceinline__ void split_A_body(const float* __restrict__ X,
                                             unsigned short* __restrict__ A2,
                                             int M, int K, int idx)
{
    int kq4 = K >> 2;
    if (idx >= M * kq4) return;
    int m = idx / kq4, kq = idx % kq4;
    float4 v = *(const float4*)&X[(size_t)m * K + kq * 4];
    ushort4 h, l;
    split1(v.x, h.x, l.x); split1(v.y, h.y, l.y);
    split1(v.z, h.z, l.z); split1(v.w, h.w, l.w);
    unsigned short* row = A2 + (size_t)m * (2 * K);
    *(ushort4*)&row[kq * 4]     = h;
    *(ushort4*)&row[K + kq * 4] = l;
}

__device__ __forceinline__ void split_Bt_body(const float* __restrict__ B0,
                                              const float* __restrict__ B1,
                                              int K, int N0, int Ntot,
                                              unsigned short* __restrict__ Bt, int idx)
{
    int total = Ntot * (K >> 2);
    if (idx >= total) return;
    int n = idx % Ntot;
    int kq = idx / Ntot;
    int k = kq * 4;
    const float* B; int nc, nb;
    if (n < N0) { B = B0; nc = n; nb = N0; }
    else        { B = B1; nc = n - N0; nb = Ntot - N0; }
    float v0 = B[(size_t)(k + 0) * nb + nc];
    float v1 = B[(size_t)(k + 1) * nb + nc];
    float v2 = B[(size_t)(k + 2) * nb + nc];
    float v3 = B[(size_t)(k + 3) * nb + nc];
    ushort4 h, l;
    split1(v0, h.x, l.x); split1(v1, h.y, l.y);
    split1(v2, h.z, l.z); split1(v3, h.w, l.w);
    unsigned short* row = Bt + (size_t)n * (3 * K);
    *(ushort4*)&row[k]         = h;
    *(ushort4*)&row[K + k]     = h;
    *(ushort4*)&row[2 * K + k] = l;
}

__device__ __forceinline__ void split_Bt1_body(const float* __restrict__ W1,
                                               const float* __restrict__ lin1W,
                                               unsigned short* __restrict__ Bt, int idx)
{
    if (idx >= 1024 * 64) return;
    int n = idx & 1023;
    int k = (idx >> 10) * 4;     // 0..252
    float v[4];
    #pragma unroll
    for (int i = 0; i < 4; ++i) {
        int kk = k + i;
        v[i] = (kk < 128) ? W1[(size_t)kk * C1 + n] : lin1W[(size_t)(kk - 128) * C1 + n];
    }
    ushort4 h, l;
    split1(v[0], h.x, l.x); split1(v[1], h.y, l.y);
    split1(v[2], h.z, l.z); split1(v[3], h.w, l.w);
    unsigned short* row = Bt + (size_t)n * 768;
    *(ushort4*)&row[k]       = h;
    *(ushort4*)&row[256 + k] = h;
    *(ushort4*)&row[512 + k] = l;
}

__global__ __launch_bounds__(256)
void prep(const float* __restrict__ x, unsigned short* __restrict__ A1stk,
          const float* __restrict__ W1, const float* __restrict__ lin1_W,
          unsigned short* __restrict__ Bt1,
          const float* __restrict__ W2, const float* __restrict__ lin2_W,
          unsigned short* __restrict__ Bt2,
          const int* __restrict__ dstp, int* __restrict__ cnt,
          const float* __restrict__ as1, const float* __restrict__ ad1,
          float* __restrict__ w1s, float* __restrict__ w1d,
          const float* __restrict__ as2, const float* __restrict__ ad2,
          float* __restrict__ v2s, float* __restrict__ v2d)
{
    const int b = blockIdx.x, t = threadIdx.x;
    const int w = t >> 6, lane = t & 63;
    if (b < 1250) {
        split_A_body(x, A1stk, NN, FIN, b * 256 + t);
    } else if (b < 1506) {
        split_Bt1_body(W1, lin1_W, Bt1, (b - 1250) * 256 + t);
    } else if (b < 2018) {
        split_Bt_body(W2, lin2_W, C1, D2, 512, Bt2, (b - 1506) * 256 + t);
    } else if (b < 2683) {
        int e = (b - 2018) * 256 + t;
        if (e < ETOT) {
            int d = (e < EE) ? dstp[e] : (e - EE);
            atomicAdd(&cnt[d], 1);
        }
    } else if (b < 2939) {
        int gw = (b - 2683) * 4 + w;
        int k = gw >> 3, rem = gw & 7, h = rem >> 1, issd = rem & 1;
        const float* a = issd ? ad1 : as1;
        float4 wv = *(const float4*)&W1[(size_t)k * C1 + h * 256 + lane * 4];
        float4 av = *(const float4*)&a[h * 256 + lane * 4];
        float s = wv.x * av.x + wv.y * av.y + wv.z * av.z + wv.w * av.w;
        #pragma unroll
        for (int off = 32; off; off >>= 1) s += __shfl_xor(s, off);
        if (lane == 0) (issd ? w1d : w1s)[k * 4 + h] = s;
    } else {
        int gw = (b - 2939) * 4 + w;
        int k = gw >> 1, issd = gw & 1;
        const float* a = issd ? ad2 : as2;
        float4 wv = *(const float4*)&W2[(size_t)k * D2 + lane * 4];
        float4 av = *(const float4*)&a[lane * 4];
        float s = wv.x * av.x + wv.y * av.y + wv.z * av.z + wv.w * av.w;
        #pragma unroll
        for (int off = 32; off; off >>= 1) s += __shfl_xor(s, off);
        if (lane == 0) (issd ? v2d : v2s)[k] = s;
    }
}

// ================= GEMMs =================
__device__ __forceinline__ void glds16(const void* g, void* l)
{
    __builtin_amdgcn_global_load_lds((const __attribute__((address_space(1))) void*)g,
                                     (__attribute__((address_space(3))) void*)l, 16, 0, 0);
}

// ---- layer-1 GEMM: per-head A = [px_h | x] split-bf16, keff=768, out = ELU(.)+biases
__global__ __launch_bounds__(256)
void gemm_l1(const unsigned short* __restrict__ Apx,
             const unsigned short* __restrict__ Ax,
             const unsigned short* __restrict__ Bt,
             unsigned short* __restrict__ h1split,
             int M, const float* __restrict__ bias0, const float* __restrict__ bias1)
{
    constexpr int BM = 128, BN = 128, BK = 32;
    constexpr int FJ = 4, FI = 4;
    constexpr int SLOTS = 4, SMASK = 3, SWSH = 1;
    constexpr int RPC = 16, ACH = 8, CPW = 4;
    constexpr int ABUF = BM * BK, BBUF = BN * BK;
    __shared__ __align__(16) unsigned short sA[2 * ABUF];
    __shared__ __align__(16) unsigned short sB[2 * BBUF];
    const int tid = threadIdx.x, w = tid >> 6, lane = tid & 63;
    const int cpx = gridDim.x >> 3;
    const int t0 = (blockIdx.x & 7) * cpx + (blockIdx.x >> 3);
    const int m0 = (t0 >> 3) * BM;          // ntn = 8
    const int n0 = (t0 & 7) * BN;
    const int hsel = n0 >> 8;               // head
    const int wm = w >> 1, wn = w & 1;
    f32x4 acc[FI][FJ] = {};

    const unsigned short *gx[CPW], *gpx[CPW], *gb[CPW];
    int lofs[CPW]; bool isa[CPW];
    {
        const int r = lane / SLOTS, sl = lane % SLOTS;
        const int ssl = sl ^ ((r >> SWSH) & SMASK);
        #pragma unroll
        for (int cc = 0; cc < CPW; ++cc) {
            int c = w * CPW + cc;
            if (c < ACH) {
                int gm = m0 + c * RPC + r; if (gm >= M) gm = M - 1;
                gx[cc]  = Ax  + (size_t)gm * 256 + ssl * 8;
                gpx[cc] = Apx + (size_t)gm * 1024 + hsel * 256 + ssl * 8;
                gb[cc]  = nullptr;
                lofs[cc] = c * 512;
                isa[cc] = true;
            } else {
                int gn = n0 + (c - ACH) * RPC + r;
                gx[cc] = gpx[cc] = nullptr;
                gb[cc] = Bt + (size_t)gn * 768 + ssl * 8;
                lofs[cc] = (c - ACH) * 512;
                isa[cc] = false;
            }
        }
    }

    const int rAl = wm * 64 + (lane & 15);
    const int rBl = wn * 64 + (lane & 15);
    const int sIdx = lane >> 4;
    const int nit = 768 / BK;               // 24
    int cur = 0;

    auto stage = [&](int kk, int buf) {
        int rr = kk >> 7;                   // 0..5
        bool px = !(rr & 1);
        int off = px ? ((rr == 2) ? 128 : 0) : ((rr == 3) ? 128 : 0);
        int kin = kk & 127;
        #pragma unroll
        for (int cc = 0; cc < CPW; ++cc) {
            if (isa[cc]) glds16((px ? gpx[cc] : gx[cc]) + off + kin, sA + buf * ABUF + lofs[cc]);
            else         glds16(gb[cc] + kk,                         sB + buf * BBUF + lofs[cc]);
        }
    };

    stage(0, 0);
    __syncthreads();
    for (int it = 0; it < nit; ++it) {
        if (it + 1 < nit) stage((it + 1) * BK, cur ^ 1);
        const unsigned short* cA = sA + cur * ABUF;
        const unsigned short* cB = sB + cur * BBUF;
        bf16x8 av[FJ], bv[FI];
        #pragma unroll
        for (int f = 0; f < FI; ++f) {
            int row = rBl + f * 16;
            bv[f] = *(const bf16x8*)&cB[row * BK + ((sIdx ^ ((row >> SWSH) & SMASK)) << 3)];
        }
        #pragma unroll
        for (int f = 0; f < FJ; ++f) {
            int row = rAl + f * 16;
            av[f] = *(const bf16x8*)&cA[row * BK + ((sIdx ^ ((row >> SWSH) & SMASK)) << 3)];
        }
        #pragma unroll
        for (int fj = 0; fj < FJ; ++fj)
            #pragma unroll
            for (int fi = 0; fi < FI; ++fi)
                acc[fi][fj] = __builtin_amdgcn_mfma_f32_16x16x32_bf16(
                    bv[fi], av[fj], acc[fi][fj], 0, 0, 0);
        __syncthreads();
        cur ^= 1;
    }

    const int lrow = lane & 15;
    const int lcol = (lane >> 4) << 2;
    #pragma unroll
    for (int fj = 0; fj < FJ; ++fj) {
        int row = m0 + wm * 64 + fj * 16 + lrow;
        if (row >= M) continue;
        #pragma unroll
        for (int fi = 0; fi < FI; ++fi) {
            int col = n0 + wn * 64 + fi * 16 + lcol;
            f32x4 v = acc[fi][fj];
            const float4 g0 = *(const float4*)&bias0[col];
            const float4 g1 = *(const float4*)&bias1[col];
            v[0] += g0.x + g1.x; v[1] += g0.y + g1.y;
            v[2] += g0.z + g1.z; v[3] += g0.w + g1.w;
            #pragma unroll
            for (int i = 0; i < 4; ++i) v[i] = v[i] > 0.f ? v[i] : expm1f(v[i]);
            ushort4 hi, lo;
            split1(v[0], hi.x, lo.x); split1(v[1], hi.y, lo.y);
            split1(v[2], hi.z, lo.z); split1(v[3], hi.w, lo.w);
            unsigned short* orow = h1split + (size_t)row * 2048;
            *(ushort4*)&orow[col]        = hi;
            *(ushort4*)&orow[C1 + col]   = lo;
        }
    }
}

// ---- generic split-bf16 GEMM (layer 2), BM templated ----
template<int BM, int BN, int WM, int WN, int BK>
__global__ __launch_bounds__(256)
void gemm_split(const unsigned short* __restrict__ A, int lda, int ka2,
                const unsigned short* __restrict__ Bt, int keff,
                unsigned short* __restrict__ outPb, float* __restrict__ outR,
                int M, int nsplit, int ldR, int ntn,
                const float* __restrict__ bias0, const float* __restrict__ bias1)
{
    constexpr int WTM  = BM / WM,  WTN = BN / WN;
    constexpr int FJ   = WTM / 16, FI  = WTN / 16;
    constexpr int KS   = BK / 32;
    constexpr int SLOTS = BK / 8;
    constexpr int SMASK = SLOTS - 1;
    constexpr int SWSH  = (BK == 32) ? 1 : 0;
    constexpr int RPC  = 512 / BK;
    constexpr int ACH  = BM / RPC;
    constexpr int NCH  = (BM + BN) / RPC;
    constexpr int CPW  = NCH / 4;
    constexpr int ABUF = BM * BK, BBUF = BN * BK;

    __shared__ __align__(16) unsigned short sA[2 * ABUF];
    __shared__ __align__(16) unsigned short sB[2 * BBUF];

    const int tid = threadIdx.x;
    const int w = tid >> 6, lane = tid & 63;

    const int cpx = gridDim.x >> 3;
    const int t0  = (blockIdx.x & 7) * cpx + (blockIdx.x >> 3);
    const int m0 = (t0 / ntn) * BM;
    const int n0 = (t0 % ntn) * BN;
    const int wm = w / WN, wn = w % WN;

    f32x4 acc[FI][FJ] = {};

    const unsigned short* gp[CPW];
    int lofs[CPW];
    bool isa[CPW];
    {
        const int r  = lane / SLOTS;
        const int sl = lane % SLOTS;
        const int ssl = sl ^ ((r >> SWSH) & SMASK);
        #pragma unroll
        for (int cc = 0; cc < CPW; ++cc) {
            int c = w * CPW + cc;
            if (c < ACH) {
                int gm = m0 + c * RPC + r; if (gm >= M) gm = M - 1;
                gp[cc]   = A + (size_t)gm * lda + ssl * 8;
                lofs[cc] = c * 512;
                isa[cc]  = true;
            } else {
                int gn = n0 + (c - ACH) * RPC + r;
                gp[cc]   = Bt + (size_t)gn * keff + ssl * 8;
                lofs[cc] = (c - ACH) * 512;
                isa[cc]  = false;
            }
        }
    }

    const int rAl = wm * WTM + (lane & 15);
    const int rBl = wn * WTN + (lane & 15);
    const int koff = (lane >> 4) * 8;
    const int nit = keff / BK;
    int cur = 0;

    #pragma unroll
    for (int cc = 0; cc < CPW; ++cc)
        glds16(gp[cc], (isa[cc] ? sA : sB) + lofs[cc]);
    __syncthreads();

    for (int it = 0; it < nit; ++it) {
        if (it + 1 < nit) {
            int kn = (it + 1) * BK;
            int kAn = (kn >= ka2) ? (kn - ka2) : kn;
            #pragma unroll
            for (int cc = 0; cc < CPW; ++cc) {
                unsigned short* dst = (isa[cc] ? sA + (cur ^ 1) * ABUF
                                               : sB + (cur ^ 1) * BBUF) + lofs[cc];
                glds16(gp[cc] + (isa[cc] ? kAn : kn), dst);
            }
        }
        const unsigned short* cA = sA + cur * ABUF;
        const unsigned short* cB = sB + cur * BBUF;
        #pragma unroll
        for (int ks = 0; ks < KS; ++ks) {
            const int sIdx = (ks * 32 + koff) >> 3;
            bf16x8 av[FJ], bv[FI];
            #pragma unroll
            for (int f = 0; f < FI; ++f) {
                int row = rBl + f * 16;
                bv[f] = *(const bf16x8*)&cB[row * BK + ((sIdx ^ ((row >> SWSH) & SMASK)) << 3)];
            }
            #pragma unroll
            for (int f = 0; f < FJ; ++f) {
                int row = rAl + f * 16;
                av[f] = *(const bf16x8*)&cA[row * BK + ((sIdx ^ ((row >> SWSH) & SMASK)) << 3)];
            }
            #pragma unroll
            for (int fj = 0; fj < FJ; ++fj)
                #pragma unroll
                for (int fi = 0; fi < FI; ++fi)
                    acc[fi][fj] = __builtin_amdgcn_mfma_f32_16x16x32_bf16(
                        bv[fi], av[fj], acc[fi][fj], 0, 0, 0);
        }
        __syncthreads();
        cur ^= 1;
    }

    const int lrow = lane & 15;
    const int lcol = (lane >> 4) << 2;
    #pragma unroll
    for (int fj = 0; fj < FJ; ++fj) {
        int row = m0 + wm * WTM + fj * 16 + lrow;
        if (row >= M) continue;
        #pragma unroll
        for (int fi = 0; fi < FI; ++fi) {
            int col = n0 + wn * WTN + fi * 16 + lcol;
            f32x4 v = acc[fi][fj];
            if (col < nsplit) {
                ushort4 o;
                o.x = f2b(v[0]); o.y = f2b(v[1]); o.z = f2b(v[2]); o.w = f2b(v[3]);
                *(ushort4*)&outPb[(size_t)row * nsplit + col] = o;
            } else {
                int c = col - nsplit;
                const float4 g0 = *(const float4*)&bias0[c];
                const float4 g1 = *(const float4*)&bias1[c];
                v[0] += g0.x + g1.x; v[1] += g0.y + g1.y;
                v[2] += g0.z + g1.z; v[3] += g0.w + g1.w;
                *(f32x4*)&outR[(size_t)row * ldR + c] = v;
            }
        }
    }
}

// ================= scores + scan (fused) =================
__global__ __launch_bounds__(256)
void s1_scores_scan(const float* __restrict__ x, const float* __restrict__ w1s,
                    const float* __restrict__ w1d, float* __restrict__ s_src,
                    float* __restrict__ s_dst,
                    const int* __restrict__ cnt, int* __restrict__ row_ptr)
{
    const int b = blockIdx.x;
    if (b < (NN + 3) / 4) {
        const int n = b * 4 + (threadIdx.x >> 6);
        if (n >= NN) return;
        const int lane = threadIdx.x & 63;
        float2 xv = *(const float2*)&x[(size_t)n * FIN + lane * 2];
        float4 wa = *(const float4*)&w1s[(lane * 2) * 4];
        float4 wb = *(const float4*)&w1s[(lane * 2 + 1) * 4];
        float4 da = *(const float4*)&w1d[(lane * 2) * 4];
        float4 db = *(const float4*)&w1d[(lane * 2 + 1) * 4];
        float ss[4] = { xv.x * wa.x + xv.y * wb.x, xv.x * wa.y + xv.y * wb.y,
                        xv.x * wa.z + xv.y * wb.z, xv.x * wa.w + xv.y * wb.w };
        float sd[4] = { xv.x * da.x + xv.y * db.x, xv.x * da.y + xv.y * db.y,
                        xv.x * da.z + xv.y * db.z, xv.x * da.w + xv.y * db.w };
        #pragma unroll
        for (int off = 32; off; off >>= 1) {
            #pragma unroll
            for (int h = 0; h < 4; ++h) {
                ss[h] += __shfl_xor(ss[h], off);
                sd[h] += __shfl_xor(sd[h], off);
            }
        }
        if (lane == 0) {
            #pragma unroll
            for (int h = 0; h < 4; ++h) {
                s_src[n * NH1 + h] = ss[h];
                s_dst[n * NH1 + h] = sd[h];
            }
        }
    } else {
        __shared__ int part[256];
        const int t = threadIdx.x;
        int local[40];
        int s = 0;
        #pragma unroll
        for (int j = 0; j < 40; ++j) {
            int idx = t * 40 + j;
            local[j] = s;
            s += (idx < NN) ? cnt[idx] : 0;
        }
        part[t] = s;
        __syncthreads();
        for (int off = 1; off < 256; off <<= 1) {
            int v = (t >= off) ? part[t - off] : 0;
            __syncthreads();
            part[t] += v;
            __syncthreads();
        }
        int prefix = (t > 0) ? part[t - 1] : 0;
        #pragma unroll
        for (int j = 0; j < 40; ++j) {
            int idx = t * 40 + j;
            if (idx < NN) row_ptr[idx] = prefix + local[j];
        }
        if (t == 0) row_ptr[NN] = ETOT;
    }
}

// ====== CSR scatter + edge-parallel sc1 precompute (post-lrelu, CSR order) ======
__global__ void scatter_edges(const int* __restrict__ srcp, const int* __restrict__ dstp,
                              const int* __restrict__ row_ptr, int* __restrict__ fill,
                              int* __restrict__ csr_src, int* __restrict__ csr_eid,
                              const float* __restrict__ s_src1,
                              const float* __restrict__ s_dst1,
                              float* __restrict__ sc1)
{
    int e = blockIdx.x * 256 + threadIdx.x;
    if (e >= ETOT) return;
    int s, d;
    if (e < EE) { s = srcp[e]; d = dstp[e]; } else { s = d = e - EE; }
    int pos = row_ptr[d] + atomicAdd(&fill[d], 1);
    csr_src[pos] = s;
    csr_eid[pos] = e;
    float4 ss = *(const float4*)&s_src1[s * 4];
    float4 dd = *(const float4*)&s_dst1[d * 4];
    float4 sc;
    sc.x = ss.x + dd.x; sc.y = ss.y + dd.y;
    sc.z = ss.z + dd.z; sc.w = ss.w + dd.w;
    sc.x = sc.x > 0.f ? sc.x : 0.2f * sc.x;
    sc.y = sc.y > 0.f ? sc.y : 0.2f * sc.y;
    sc.z = sc.z > 0.f ? sc.z : 0.2f * sc.z;
    sc.w = sc.w > 0.f ? sc.w : 0.2f * sc.w;
    *(float4*)&sc1[(size_t)pos * 4] = sc;
}

// ===== node-parallel m,1/z for layer 1 + fused alpha1 write (contiguous sc1) =====
__global__ __launch_bounds__(256)
void mz1_alpha(const float* __restrict__ sc1, const int* __restrict__ row_ptr,
               const int* __restrict__ csr_eid, float* __restrict__ mz1,
               float* __restrict__ alpha_out)
{
    const int n = blockIdx.x * 4 + (threadIdx.x >> 6);
    if (n >= NN) return;
    const int lane = threadIdx.x & 63;
    const int start = row_ptr[n], end = row_ptr[n + 1];
    float4 m = make_float4(-1e30f, -1e30f, -1e30f, -1e30f);
    for (int i = start + lane; i < end; i += 64) {
        float4 s = *(const float4*)&sc1[(size_t)i * 4];
        m.x = fmaxf(m.x, s.x); m.y = fmaxf(m.y, s.y);
        m.z = fmaxf(m.z, s.z); m.w = fmaxf(m.w, s.w);
    }
    #pragma unroll
    for (int off = 32; off; off >>= 1) {
        m.x = fmaxf(m.x, __shfl_xor(m.x, off));
        m.y = fmaxf(m.y, __shfl_xor(m.y, off));
        m.z = fmaxf(m.z, __shfl_xor(m.z, off));
        m.w = fmaxf(m.w, __shfl_xor(m.w, off));
    }
    float4 z = make_float4(0.f, 0.f, 0.f, 0.f);
    for (int i = start + lane; i < end; i += 64) {
        float4 s = *(const float4*)&sc1[(size_t)i * 4];
        z.x += __expf(s.x - m.x); z.y += __expf(s.y - m.y);
        z.z += __expf(s.z - m.z); z.w += __expf(s.w - m.w);
    }
    #pragma unroll
    for (int off = 32; off; off >>= 1) {
        z.x += __shfl_xor(z.x, off); z.y += __shfl_xor(z.y, off);
        z.z += __shfl_xor(z.z, off); z.w += __shfl_xor(z.w, off);
    }
    float4 iz;
    iz.x = 1.f / (z.x + 1e-16f); iz.y = 1.f / (z.y + 1e-16f);
    iz.z = 1.f / (z.z + 1e-16f); iz.w = 1.f / (z.w + 1e-16f);
    if (lane == 0) {
        *(float4*)&mz1[(size_t)n * 8]     = m;
        *(float4*)&mz1[(size_t)n * 8 + 4] = iz;
    }
    for (int i = start + lane; i < end; i += 64) {
        float4 s = *(const float4*)&sc1[(size_t)i * 4];
        float4 a;
        a.x = __expf(s.x - m.x) * iz.x;
        a.y = __expf(s.y - m.y) * iz.y;
        a.z = __expf(s.z - m.z) * iz.z;
        a.w = __expf(s.w - m.w) * iz.w;
        *(float4*)&alpha_out[(size_t)csr_eid[i] * 4] = a;
    }
}

// ======== layer-1 cooperative px gather — SINGLE PHASE (alpha inline from mz1) ========
__global__ __launch_bounds__(256)
void px_gather(const float* __restrict__ x, const float* __restrict__ sc1,
               const float* __restrict__ mz1, const int* __restrict__ row_ptr,
               const int* __restrict__ csr_src, unsigned short* __restrict__ Apx)
{
    __shared__ float red[4][16][33];
    const int n = blockIdx.x;
    const int t = threadIdx.x;
    const int w = t >> 6;
    const int lane = t & 63;
    const int start = row_ptr[n], end = row_ptr[n + 1];
    const float4 m  = *(const float4*)&mz1[(size_t)n * 8];
    const float4 iz = *(const float4*)&mz1[(size_t)n * 8 + 4];

    const int slot = w * 4 + (lane >> 4);
    const int g = lane & 15;
    float acc[4][8] = {};
    for (int i = start + slot; i < end; i += 16) {
        const int s = csr_src[i];
        float4 sv = *(const float4*)&sc1[(size_t)i * 4];
        const float a0 = __expf(sv.x - m.x) * iz.x;
        const float a1 = __expf(sv.y - m.y) * iz.y;
        const float a2 = __expf(sv.z - m.z) * iz.z;
        const float a3 = __expf(sv.w - m.w) * iz.w;
        const float* xr = &x[(size_t)s * FIN + g * 8];
        float4 v0 = *(const float4*)&xr[0];
        float4 v1 = *(const float4*)&xr[4];
        float vv[8] = { v0.x, v0.y, v0.z, v0.w, v1.x, v1.y, v1.z, v1.w };
        #pragma unroll
        for (int d = 0; d < 8; ++d) {
            acc[0][d] += a0 * vv[d];
            acc[1][d] += a1 * vv[d];
            acc[2][d] += a2 * vv[d];
            acc[3][d] += a3 * vv[d];
        }
    }
    #pragma unroll
    for (int off = 16; off <= 32; off <<= 1)
        #pragma unroll
        for (int h = 0; h < 4; ++h)
            #pragma unroll
            for (int d = 0; d < 8; ++d)
                acc[h][d] += __shfl_xor(acc[h][d], off);
    if ((lane >> 4) == 0) {
        #pragma unroll
        for (int h = 0; h < 4; ++h)
            #pragma unroll
            for (int d = 0; d < 8; ++d)
                red[w][g][h * 8 + d] = acc[h][d];
    }
    __syncthreads();
    if (lane < 16) {
        float sum[8];
        #pragma unroll
        for (int d = 0; d < 8; ++d)
            sum[d] = red[0][lane][w * 8 + d] + red[1][lane][w * 8 + d]
                   + red[2][lane][w * 8 + d] + red[3][lane][w * 8 + d];
        ushort4 hi0, hi1, lo0, lo1;
        split1(sum[0], hi0.x, lo0.x); split1(sum[1], hi0.y, lo0.y);
        split1(sum[2], hi0.z, lo0.z); split1(sum[3], hi0.w, lo0.w);
        split1(sum[4], hi1.x, lo1.x); split1(sum[5], hi1.y, lo1.y);
        split1(sum[6], hi1.z, lo1.z); split1(sum[7], hi1.w, lo1.w);
        unsigned short* orow = Apx + (size_t)n * 1024 + w * 256 + lane * 8;
        *(ushort4*)&orow[0]       = hi0;
        *(ushort4*)&orow[4]       = hi1;
        *(ushort4*)&orow[128]     = lo0;
        *(ushort4*)&orow[132]     = lo1;
    }
}

// ================= layer-2 scores =================
__global__ __launch_bounds__(256)
void scores2(const unsigned short* __restrict__ h1split, const float* __restrict__ v2s,
             const float* __restrict__ v2d, float* __restrict__ s_src,
             float* __restrict__ s_dst)
{
    const int n = blockIdx.x * 4 + (threadIdx.x >> 6);
    if (n >= NN) return;
    const int lane = threadIdx.x & 63;
    const unsigned short* row = h1split + (size_t)n * 2048 + lane * 16;
    float ss = 0.f, sd = 0.f;
    #pragma unroll
    for (int q = 0; q < 16; ++q) {
        float hv = b2f(row[q]);
        ss += hv * v2s[lane * 16 + q];
        sd += hv * v2d[lane * 16 + q];
    }
    #pragma unroll
    for (int off = 32; off; off >>= 1) {
        ss += __shfl_xor(ss, off);
        sd += __shfl_xor(sd, off);
    }
    if (lane == 0) { s_src[n] = ss; s_dst[n] = sd; }
}

// ====== layer-2 softmax (scattered, LDS alpha) + 4-slot aggregate + residual ======
__global__ __launch_bounds__(64)
void aggregate2(const unsigned short* __restrict__ h2b, const float* __restrict__ s_src,
                const float* __restrict__ s_dst,
                const int* __restrict__ row_ptr, const int* __restrict__ csr_src,
                const float* __restrict__ accin, float* __restrict__ out)
{
    __shared__ float lalpha[MAXD];
    const int n = blockIdx.x;
    const int t = threadIdx.x;
    const int start = row_ptr[n], end = row_ptr[n + 1];
    const float sd = s_dst[n];

    float m = -1e30f;
    for (int i = start + t; i < end; i += 64) {
        float sc = s_src[csr_src[i]] + sd;
        sc = sc > 0.f ? sc : 0.2f * sc;
        m = fmaxf(m, sc);
    }
    #pragma unroll
    for (int off = 32; off; off >>= 1) m = fmaxf(m, __shfl_xor(m, off));
    float z = 0.f;
    for (int i = start + t; i < end; i += 64) {
        float sc = s_src[csr_src[i]] + sd;
        sc = sc > 0.f ? sc : 0.2f * sc;
        z += __expf(sc - m);
    }
    #pragma unroll
    for (int off = 32; off; off >>= 1) z += __shfl_xor(z, off);
    const float invz = 1.f / (z + 1e-16f);
    for (int i = start + t; i < end; i += 64) {
        float sc = s_src[csr_src[i]] + sd;
        sc = sc > 0.f ? sc : 0.2f * sc;
        int idx = i - start;
        if (idx < MAXD) lalpha[idx] = __expf(sc - m) * invz;
    }
    __syncthreads();

    const int slot = t >> 4, g = t & 15;
    float acc[16] = {};
    for (int i = start + slot; i < end; i += 4) {
        const int s = csr_src[i];
        const int idx = i - start;
        float a;
        if (idx < MAXD) {
            a = lalpha[idx];
        } else {
            float sc = s_src[s] + sd;
            sc = sc > 0.f ? sc : 0.2f * sc;
            a = __expf(sc - m) * invz;
        }
        const unsigned short* vr = &h2b[(size_t)s * D2 + g * 16];
        bf16x8 u0 = *(const bf16x8*)&vr[0];
        bf16x8 u1 = *(const bf16x8*)&vr[8];
        #pragma unroll
        for (int d = 0; d < 8; ++d) {
            acc[d]     += a * b2f((unsigned short)u0[d]);
            acc[8 + d] += a * b2f((unsigned short)u1[d]);
        }
    }
    #pragma unroll
    for (int off = 16; off <= 32; off <<= 1)
        #pragma unroll
        for (int d = 0; d < 16; ++d)
            acc[d] += __shfl_xor(acc[d], off);
    if (slot == 0) {
        const float* br = &accin[(size_t)n * D2 + g * 16];
        float* orow = &out[(size_t)n * D2 + g * 16];
        #pragma unroll
        for (int q = 0; q < 4; ++q) {
            float4 b = *(const float4*)&br[q * 4];
            float4 r;
            r.x = acc[q * 4 + 0] + b.x; r.y = acc[q * 4 + 1] + b.y;
            r.z = acc[q * 4 + 2] + b.z; r.w = acc[q * 4 + 3] + b.w;
            *(float4*)&orow[q * 4] = r;
        }
    }
}

extern "C" void kernel_launch(void* const* d_in, const int* in_sizes, int n_in,
                              void* d_out, int out_size, void* d_ws, size_t ws_size,
                              hipStream_t stream)
{
    const float* x        = (const float*)d_in[0];
    const int*   ei       = (const int*)  d_in[1];
    const float* W1       = (const float*)d_in[2];
    const float* att_src1 = (const float*)d_in[3];
    const float* att_dst1 = (const float*)d_in[4];
    const float* b1       = (const float*)d_in[5];
    const float* lin1_W   = (const float*)d_in[6];
    const float* lin1_b   = (const float*)d_in[7];
    const float* W2       = (const float*)d_in[8];
    const float* att_src2 = (const float*)d_in[9];
    const float* att_dst2 = (const float*)d_in[10];
    const float* b2       = (const float*)d_in[11];
    const float* lin2_W   = (const float*)d_in[12];
    const float* lin2_b   = (const float*)d_in[13];
    const int* srcp = ei;
    const int* dstp = ei + EE;

    float* out    = (float*)d_out;
    float* alpha1 = out + (size_t)NN * D2;           // [ETOT,4] region of d_out

    float* fw = (float*)d_ws;
    unsigned short* A1stk = (unsigned short*)fw; fw += (size_t)NN * 256 / 2;   // [NN][xhi|xlo]
    unsigned short* Apx   = (unsigned short*)fw; fw += (size_t)NN * 1024 / 2;  // [NN][4][pxhi|pxlo]
    unsigned short* A2stk = (unsigned short*)fw; fw += (size_t)NN * 2048 / 2;  // [NN][h1hi|h1lo]
    unsigned short* h2b   = (unsigned short*)fw; fw += (size_t)NN * 256 / 2;   // [NN][D2] bf16
    float* acc2   = fw;  fw += (size_t)NN * D2;                                 // lin2 residual
    unsigned short* Bt1 = (unsigned short*)fw; fw += (size_t)1024 * 768 / 2;   // [1024][768]
    unsigned short* Bt2 = (unsigned short*)fw; fw += (size_t)512 * 3072 / 2;   // [512][3072]
    float* w1s = fw; fw += 512;
    float* w1d = fw; fw += 512;
    float* v2s = fw; fw += 1024;
    float* v2d = fw; fw += 1024;
    float* s_src1 = fw; fw += NN * NH1;
    float* s_dst1 = fw; fw += NN * NH1;
    float* s_src2 = fw; fw += NN;
    float* s_dst2 = fw; fw += NN;
    float* sc1    = fw; fw += (size_t)ETOT * NH1;   // [ETOT][4] post-lrelu scores, CSR order
    float* mz1    = fw; fw += (size_t)NN * 8;       // per-node [m x4 | invz x4]
    int* ip      = (int*)fw;
    int* cnt     = ip;  ip += NN;
    int* fill    = ip;  ip += NN;
    int* row_ptr = ip;  ip += NN + 4;
    int* csr_src = ip;  ip += ETOT;
    int* csr_eid = ip;  ip += ETOT;

    hipMemsetAsync(cnt, 0, 2 * NN * sizeof(int), stream);

    // ---- fused prep ----
    prep<<<3451, 256, 0, stream>>>(x, A1stk, W1, lin1_W, Bt1, W2, lin2_W, Bt2,
                                   dstp, cnt, att_src1, att_dst1, w1s, w1d,
                                   att_src2, att_dst2, v2s, v2d);

    // ---- layer-1 node scores + CSR scan (fused) ----
    s1_scores_scan<<<(NN + 3) / 4 + 1, 256, 0, stream>>>(x, w1s, w1d, s_src1, s_dst1,
                                                         cnt, row_ptr);

    // ---- CSR scatter + contiguous sc1 precompute ----
    scatter_edges<<<(ETOT + 255) / 256, 256, 0, stream>>>(srcp, dstp, row_ptr, fill,
                                                          csr_src, csr_eid,
                                                          s_src1, s_dst1, sc1);

    // ---- layer-1 softmax stats + fused alpha1 write (alpha1 -> d_out) ----
    mz1_alpha<<<(NN + 3) / 4, 256, 0, stream>>>(sc1, row_ptr, csr_eid, mz1, alpha1);

    // ---- layer-1 single-phase cooperative 128-dim gather ----
    px_gather<<<NN, 256, 0, stream>>>(x, sc1, mz1, row_ptr, csr_src, Apx);

    // ---- layer-1 GEMM: [px_h|x] @ [W1_h; lin1W] + biases, ELU, split -> A2stk ----
    gemm_l1<<<79 * 8, 256, 0, stream>>>(Apx, A1stk, Bt1, A2stk, NN, lin1_b, b1);

    // ---- layer-2 scores ----
    scores2<<<(NN + 3) / 4, 256, 0, stream>>>(A2stk, v2s, v2d, s_src2, s_dst2);

    // ---- layer-2 GEMM (fused W2|lin2_W), BM=128 BN=64 BK=64 ----
    gemm_split<128, 64, 4, 1, 64><<<79 * 8, 256, 0, stream>>>(
        A2stk, 2 * C1, 2 * C1, Bt2, 3 * C1, h2b, acc2, NN, D2, D2, 8, lin2_b, b2);

    // ---- layer-2 softmax + aggregate -> out ----
    aggregate2<<<NN, 64, 0, stream>>>(h2b, s_src2, s_dst2, row_ptr, csr_src, acc2, out);
}